// Round 6
// baseline (507.322 us; speedup 1.0000x reference)
//
#include <hip/hip_runtime.h>
#include <cstdint>
#include <cstddef>

#define NFEAT 128
#define KBUCK 1024

typedef __attribute__((ext_vector_type(8))) short bf16x8;
typedef __attribute__((ext_vector_type(4))) float f32x4;

// bf16 <-> f32 helpers (RNE, no NaN handling needed — activations are finite)
__device__ __forceinline__ unsigned short f2bf(float x) {
    union { float f; unsigned u; } v; v.f = x;
    unsigned r = v.u + 0x7fffu + ((v.u >> 16) & 1u);
    return (unsigned short)(r >> 16);
}
__device__ __forceinline__ float bf2f(unsigned short b) {
    union { unsigned u; float f; } v; v.u = ((unsigned)b) << 16;
    return v.f;
}
__device__ __forceinline__ float u2f(unsigned u) {
    union { unsigned u; float f; } v; v.u = u; return v.f;
}

// ---------------- preprocessing kernels ----------------

// one launch zeroes everything that needs zeroing:
// deg_src[n], dst_btot[KBUCK], Xb row n, X1b row n, csr_e slack
__global__ __launch_bounds__(256) void zero_multi(
    int* __restrict__ a, int na, int* __restrict__ b, int nb,
    int* __restrict__ c, int nc, int* __restrict__ d, int nd_,
    int* __restrict__ e, int ne_) {
    int i = blockIdx.x * 256 + threadIdx.x;
    int st = gridDim.x * 256;
    for (int k = i; k < na; k += st) a[k] = 0;
    if (i < nb) b[i] = 0;
    if (i < nc) c[i] = 0;
    if (i < nd_) d[i] = 0;
    if (i < ne_) e[i] = 0;
}

__global__ void cast_bf16_kernel(const float* __restrict__ x, unsigned short* __restrict__ y, int n4) {
    int i = blockIdx.x * blockDim.x + threadIdx.x;
    if (i < n4) {
        float4 v = ((const float4*)x)[i];
        ushort4 o;
        o.x = f2bf(v.x); o.y = f2bf(v.y); o.z = f2bf(v.z); o.w = f2bf(v.w);
        ((ushort4*)y)[i] = o;
    }
}

// Pack Wcat (256 x NCOL: rows 0..127 = gcW, 128..255 = resW; fp32) into bf16 MFMA
// B-fragment order for K=256 GEMM:
// Wf[((kb*NT + nt)*64 + lane)*8 + j] = Wcat[kb*32 + (lane>>4)*8 + j][nt*16 + (lane&15)]
template <int NCOL>
__global__ void prep_wf2(const float* __restrict__ gcW, const float* __restrict__ resW,
                         unsigned short* __restrict__ Wf) {
    constexpr int NT = NCOL / 16;
    int tid = blockIdx.x * 256 + threadIdx.x;
    if (tid >= 256 * NCOL) return;
    int k = tid / NCOL, c = tid % NCOL;
    float v = (k < 128) ? gcW[k * NCOL + c] : resW[(k - 128) * NCOL + c];
    int kb = k >> 5, koff = k & 31, quad = koff >> 3, j = koff & 7;
    int nt = c >> 4, ncol = c & 15, lane = quad * 16 + ncol;
    Wf[((kb * NT + nt) * 64 + lane) * 8 + j] = f2bf(v);
}

// ---------------- graph preprocessing (round-14: src-side machinery deleted) ----------------
// dst side keeps the bucketed radix build (LDS hist -> scan -> partition -> per-bucket
// counting sort). src side only ever needed DEGREES, so it collapses to one global
// atomicAdd per edge here (1.6M random L2 atomics), and norm_s is computed inline in
// build_dst from deg_src.

__global__ __launch_bounds__(256) void hist_deg(
    const int* __restrict__ src, const int* __restrict__ dst, int ne, int D,
    int* __restrict__ dst_btot, int* __restrict__ deg_src) {
    __shared__ int hd[KBUCK];
    const int t = threadIdx.x;
    const int tile0 = blockIdx.x * 4096;
    for (int i = t; i < KBUCK; i += 256) hd[i] = 0;
    __syncthreads();
    #pragma unroll
    for (int j = 0; j < 16; j++) {
        int e = tile0 + j * 256 + t;
        if (e < ne) {
            atomicAdd(&hd[(unsigned)dst[e] / (unsigned)D], 1);
            atomicAdd(&deg_src[src[e]], 1);          // random global (L2) atomic
        }
    }
    __syncthreads();
    for (int i = t; i < KBUCK; i += 256) {
        if (hd[i]) atomicAdd(&dst_btot[i], hd[i]);
    }
}

__global__ __launch_bounds__(KBUCK) void scan_dst(
    const int* __restrict__ dst_btot, int* __restrict__ dst_base,
    int* __restrict__ dst_cursor, int* __restrict__ row_ptr, int n, int ne) {
    __shared__ int t1[KBUCK];
    const int t = threadIdx.x;
    int v = dst_btot[t];
    t1[t] = v;
    for (int off = 1; off < KBUCK; off <<= 1) {
        __syncthreads();
        int a = (t >= off) ? t1[t - off] : 0;
        __syncthreads();
        t1[t] += a;
    }
    __syncthreads();
    int e = t1[t] - v;
    dst_base[t] = e;
    dst_cursor[t] = e;
    if (t == KBUCK - 1) {
        dst_base[KBUCK] = t1[t];
        row_ptr[n] = ne;
    }
}

__global__ __launch_bounds__(256) void partition_dst(
    const int* __restrict__ src, const int* __restrict__ dst, int ne, int D,
    int* __restrict__ dst_cursor, uint2* __restrict__ ebuf) {
    __shared__ int hist[KBUCK];
    __shared__ int gbase[KBUCK];
    const int t = threadIdx.x;
    const int tile0 = blockIdx.x * 4096;

    for (int i = t; i < KBUCK; i += 256) hist[i] = 0;
    __syncthreads();

    int s[16], d[16], r[16];
    #pragma unroll
    for (int j = 0; j < 16; j++) {
        int e = tile0 + j * 256 + t;
        if (e < ne) {
            s[j] = src[e];
            d[j] = dst[e];
            int b = (int)((unsigned)d[j] / (unsigned)D);
            r[j] = atomicAdd(&hist[b], 1);
        }
    }
    __syncthreads();
    for (int i = t; i < KBUCK; i += 256) {
        int c = hist[i];
        gbase[i] = c ? atomicAdd(&dst_cursor[i], c) : 0;
    }
    __syncthreads();
    #pragma unroll
    for (int j = 0; j < 16; j++) {
        int e = tile0 + j * 256 + t;
        if (e < ne) {
            int b = (int)((unsigned)d[j] / (unsigned)D);
            ebuf[gbase[b] + r[j]] = make_uint2((unsigned)s[j], (unsigned)d[j]);
        }
    }
}

// build_dst emits fused CSR entries {src, norm_s[src]} with norm_s computed inline
// from deg_src (rsqrt per edge). Also writes row_ptr and norm_d.
__global__ __launch_bounds__(256) void build_dst(
    const uint2* __restrict__ ebuf, const int* __restrict__ dst_base,
    const int* __restrict__ deg_src,
    int n, int D, int* __restrict__ row_ptr, float* __restrict__ norm_d,
    uint2* __restrict__ csr_e) {
    __shared__ int cnt[128], sc[128], rp[128], rank[128];
    const int b = blockIdx.x;
    const int d_lo = b * D;
    if (d_lo >= n) return;
    const int d_hi = (d_lo + D < n) ? d_lo + D : n;
    const int e0 = dst_base[b], e1 = dst_base[b + 1];
    const int t = threadIdx.x;

    if (t < 128) { cnt[t] = 0; rank[t] = 0; }
    __syncthreads();
    for (int i = e0 + t; i < e1; i += 256)
        atomicAdd(&cnt[(int)ebuf[i].y - d_lo], 1);
    __syncthreads();
    if (t < 128) sc[t] = cnt[t];
    __syncthreads();
    for (int off = 1; off < 128; off <<= 1) {
        int v = (t < 128 && t >= off) ? sc[t - off] : 0;
        __syncthreads();
        if (t < 128) sc[t] += v;
        __syncthreads();
    }
    if (t < 128) {
        rp[t] = e0 + sc[t] - cnt[t];   // exclusive
        int d = d_lo + t;
        if (d < d_hi) {
            row_ptr[d] = rp[t];
            norm_d[d] = rsqrtf(fmaxf((float)cnt[t], 1.0f));
        }
    }
    __syncthreads();
    for (int i = e0 + t; i < e1; i += 256) {
        uint2 ed = ebuf[i];
        int dd = (int)ed.y - d_lo;
        int r = atomicAdd(&rank[dd], 1);
        float nsv = rsqrtf(fmaxf((float)deg_src[(int)ed.x], 1.0f));
        csr_e[rp[dd] + r] = make_uint2(ed.x, __float_as_uint(nsv));
    }
}

// ---------------- aggregate-first SpMM: U = [norm_d .* (A@(norm_s.*x)) | A@x] ----------------
// Round-3 structure verbatim (best measured: 60.9us). One wave per node, 16-edge
// chunks; entries via 16 x s_load_dwordx2 (SMEM, wave-uniform, lands in SGPRs);
// invalid edges redirect to zeroed row X[n] with weight 0 via scalar cselect;
// gathers are saddr-form dword loads (1 VALU addr op per edge).

__global__ __launch_bounds__(256) void spmm_pre(
    const unsigned short* __restrict__ X, const int* __restrict__ row_ptr,
    const uint2* __restrict__ csr_e, const float* __restrict__ norm_d,
    unsigned short* __restrict__ U, int n) {
    const int wid = (blockIdx.x * 256 + threadIdx.x) >> 6;
    const int lane = threadIdx.x & 63;
    if (wid >= n) return;

    const int e0 = __builtin_amdgcn_readfirstlane(row_ptr[wid]);
    const int e1 = __builtin_amdgcn_readfirstlane(row_ptr[wid + 1]);
    const float nd = norm_d[wid];

    float ap0 = 0.f, ap1 = 0.f, as0 = 0.f, as1 = 0.f;
    const unsigned voff = (unsigned)(lane << 2);   // byte offset within row
    const char* Xc = (const char*)X;

    for (int c = e0; c < e1; c += 16) {
        uint64_t E0, E1, E2, E3, E4, E5, E6, E7, E8, E9, Ea, Eb, Ec, Ed, Ee, Ef;
        {
            uint64_t ep = (uint64_t)(const char*)(csr_e + c);
            asm volatile(
                "s_load_dwordx2 %[o0], %[a], 0x0\n\t"
                "s_load_dwordx2 %[o1], %[a], 0x8\n\t"
                "s_load_dwordx2 %[o2], %[a], 0x10\n\t"
                "s_load_dwordx2 %[o3], %[a], 0x18\n\t"
                "s_load_dwordx2 %[o4], %[a], 0x20\n\t"
                "s_load_dwordx2 %[o5], %[a], 0x28\n\t"
                "s_load_dwordx2 %[o6], %[a], 0x30\n\t"
                "s_load_dwordx2 %[o7], %[a], 0x38\n\t"
                "s_load_dwordx2 %[o8], %[a], 0x40\n\t"
                "s_load_dwordx2 %[o9], %[a], 0x48\n\t"
                "s_load_dwordx2 %[oa], %[a], 0x50\n\t"
                "s_load_dwordx2 %[ob], %[a], 0x58\n\t"
                "s_load_dwordx2 %[oc], %[a], 0x60\n\t"
                "s_load_dwordx2 %[od], %[a], 0x68\n\t"
                "s_load_dwordx2 %[oe], %[a], 0x70\n\t"
                "s_load_dwordx2 %[of], %[a], 0x78\n\t"
                "s_waitcnt lgkmcnt(0)"
                : [o0] "=&s"(E0), [o1] "=&s"(E1), [o2] "=&s"(E2), [o3] "=&s"(E3),
                  [o4] "=&s"(E4), [o5] "=&s"(E5), [o6] "=&s"(E6), [o7] "=&s"(E7),
                  [o8] "=&s"(E8), [o9] "=&s"(E9), [oa] "=&s"(Ea), [ob] "=&s"(Eb),
                  [oc] "=&s"(Ec), [od] "=&s"(Ed), [oe] "=&s"(Ee), [of] "=&s"(Ef)
                : [a] "s"(ep)
                : "memory");
        }

        unsigned q[16];
        float wv[16];

#define PREP(i, Ei)                                                             \
        {                                                                       \
            int sv = (int)(unsigned)(Ei);                                       \
            unsigned wu = (unsigned)((Ei) >> 32);                               \
            const bool val = (c + i) < e1;      /* wave-uniform scalar */       \
            sv = val ? sv : n;                  /* s_cselect */                 \
            wu = val ? wu : 0u;                 /* s_cselect */                 \
            wv[i] = u2f(wu);                                                    \
            unsigned off = (((unsigned)sv) << 8) + voff;  /* v_lshl_add_u32 */  \
            q[i] = *(const unsigned*)(Xc + off);          /* saddr-form load */ \
        }
        PREP(0, E0)  PREP(1, E1)  PREP(2, E2)  PREP(3, E3)
        PREP(4, E4)  PREP(5, E5)  PREP(6, E6)  PREP(7, E7)
        PREP(8, E8)  PREP(9, E9)  PREP(10, Ea) PREP(11, Eb)
        PREP(12, Ec) PREP(13, Ed) PREP(14, Ee) PREP(15, Ef)
#undef PREP

        #pragma unroll
        for (int i = 0; i < 16; i++) {
            unsigned qq = q[i];
            float x0 = u2f(qq << 16);
            float x1 = u2f(qq & 0xffff0000u);
            ap0 += x0; ap1 += x1;
            as0 = fmaf(wv[i], x0, as0);
            as1 = fmaf(wv[i], x1, as1);
        }
    }

    ushort2 gc, rs;
    gc.x = f2bf(nd * as0); gc.y = f2bf(nd * as1);
    rs.x = f2bf(ap0);      rs.y = f2bf(ap1);
    unsigned short* Ur = U + (size_t)wid * 256;
    *(ushort2*)(Ur + lane * 2) = gc;
    *(ushort2*)(Ur + 128 + lane * 2) = rs;
}

// ---------------- MFMA GEMM: y = U @ [W;R] + b (+relu), K=256 ----------------
// Round-4 structure verbatim: NO LDS staging — Wf is 64KB and L2-resident;
// B-fragments load straight from global per MFMA. U: [M,256] bf16; Wf
// fragment-major (prep_wf2). mfma_f32_16x16x32_bf16 layouts (HW-verified m89/m91):
// A[m=lane&15][k=(lane>>4)*8+j], C/D col=lane&15, row=(lane>>4)*4+reg.

template <int NCOL, bool RELU, bool OUT_BF16>
__global__ __launch_bounds__(256) void gemm_mfma(
    const unsigned short* __restrict__ U, int M,
    const unsigned short* __restrict__ Wf,
    const float* __restrict__ bias, void* __restrict__ outv) {
    constexpr int NT = NCOL / 16;

    const int t = threadIdx.x;
    const int wave = t >> 6, lane = t & 63;
    const int r0 = blockIdx.x * 64 + wave * 16;

    // A fragments (rows am = r0 + (lane&15), k = kb*32 + (lane>>4)*8 + j)
    const int am = r0 + (lane & 15);
    const int kq = (lane >> 4) * 8;
    bf16x8 afrag[8];
    if (am < M) {
        const unsigned short* ap = U + (size_t)am * 256 + kq;
        #pragma unroll
        for (int kb = 0; kb < 8; kb++)
            afrag[kb] = *(const bf16x8*)(ap + kb * 32);
    } else {
        #pragma unroll
        for (int kb = 0; kb < 8; kb++) afrag[kb] = bf16x8{};
    }

    const int orow = r0 + (lane >> 4) * 4;
    const bf16x8* Wv = (const bf16x8*)Wf;

    #pragma unroll 1
    for (int nt = 0; nt < NT; nt++) {
        f32x4 acc = {0.f, 0.f, 0.f, 0.f};
        #pragma unroll
        for (int kb = 0; kb < 8; kb++) {
            bf16x8 b = Wv[(kb * NT + nt) * 64 + lane];
            acc = __builtin_amdgcn_mfma_f32_16x16x32_bf16(afrag[kb], b, acc, 0, 0, 0);
        }
        const int gcol = nt * 16 + (lane & 15);
        const float bv = bias[gcol];
        #pragma unroll
        for (int r = 0; r < 4; r++) {
            int gm = orow + r;
            if (gm < M) {
                float v = acc[r] + bv;
                if (RELU) v = fmaxf(v, 0.f);
                if constexpr (OUT_BF16)
                    ((unsigned short*)outv)[(size_t)gm * NCOL + gcol] = f2bf(v);
                else
                    ((float*)outv)[(size_t)gm * NCOL + gcol] = v;
            }
        }
    }
}

// ---------------- launch ----------------

extern "C" void kernel_launch(void* const* d_in, const int* in_sizes, int n_in,
                              void* d_out, int out_size, void* d_ws, size_t ws_size,
                              hipStream_t stream) {
    const float* raw_x  = (const float*)d_in[0];
    const int*   src    = (const int*)d_in[1];
    const int*   dst    = (const int*)d_in[2];
    const float* gc_w0  = (const float*)d_in[3];
    const float* gc_b0  = (const float*)d_in[4];
    const float* gc_w1  = (const float*)d_in[5];
    const float* gc_b1  = (const float*)d_in[6];
    const float* gc_w2  = (const float*)d_in[7];
    const float* gc_b2  = (const float*)d_in[8];
    const float* res_w0 = (const float*)d_in[9];
    const float* res_w1 = (const float*)d_in[10];
    const float* res_w2 = (const float*)d_in[11];

    const int n  = in_sizes[0] / NFEAT;   // 100000
    const int ne = in_sizes[1];           // 1600000
    float* out = (float*)d_out;
    const int D = (n + KBUCK - 1) / KBUCK;   // nodes per bucket (98, <=128)

    // workspace layout (Xb/X1b have an extra zeroed row n; csr_e has 48 slack entries)
    char* w = (char*)d_ws;
    unsigned short* U   = (unsigned short*)w; w += (size_t)n * 256 * sizeof(unsigned short);       // 51.2 MB
    unsigned short* Xb  = (unsigned short*)w; w += (size_t)(n + 1) * 128 * sizeof(unsigned short); // 25.6 MB
    unsigned short* X1b = (unsigned short*)w; w += (size_t)(n + 1) * 128 * sizeof(unsigned short); // 25.6 MB
    int* deg_src = (int*)w;      w += (size_t)n * sizeof(int);
    float* norm_d = (float*)w;   w += (size_t)n * sizeof(float);
    int* row_ptr = (int*)w;      w += (size_t)(n + 1) * sizeof(int);
    uint2* csr_e = (uint2*)w;    w += (size_t)(ne + 48) * sizeof(uint2);   // 12.8 MB {src, ns}
    uint2* ebuf = (uint2*)w;     w += (size_t)ne * sizeof(uint2);          // 12.8 MB
    int* dst_btot = (int*)w;     w += KBUCK * sizeof(int);
    int* dst_base = (int*)w;     w += (KBUCK + 1) * sizeof(int);
    int* dst_cursor = (int*)w;   w += KBUCK * sizeof(int);
    unsigned short* Wf0 = (unsigned short*)w; w += 256 * 128 * sizeof(unsigned short);
    unsigned short* Wf1 = (unsigned short*)w; w += 256 * 128 * sizeof(unsigned short);
    unsigned short* Wf2 = (unsigned short*)w; w += 256 * 64 * sizeof(unsigned short);

    const int tiles = (ne + 4095) / 4096;

    // --- preprocessing: bf16 cast, weight fragments, degrees + bucketed dst CSR ---
    cast_bf16_kernel<<<(n * (NFEAT / 4) + 255) / 256, 256, 0, stream>>>(raw_x, Xb, n * (NFEAT / 4));
    zero_multi<<<(n + 255) / 256, 256, 0, stream>>>(
        deg_src, n, dst_btot, KBUCK,
        (int*)(Xb + (size_t)n * 128), 64,
        (int*)(X1b + (size_t)n * 128), 64,
        (int*)(csr_e + ne), 96);
    prep_wf2<128><<<128, 256, 0, stream>>>(gc_w0, res_w0, Wf0);
    prep_wf2<128><<<128, 256, 0, stream>>>(gc_w1, res_w1, Wf1);
    prep_wf2<64><<<64, 256, 0, stream>>>(gc_w2, res_w2, Wf2);
    hist_deg<<<tiles, 256, 0, stream>>>(src, dst, ne, D, dst_btot, deg_src);
    scan_dst<<<1, KBUCK, 0, stream>>>(dst_btot, dst_base, dst_cursor, row_ptr, n, ne);
    partition_dst<<<tiles, 256, 0, stream>>>(src, dst, ne, D, dst_cursor, ebuf);
    build_dst<<<KBUCK, 256, 0, stream>>>(ebuf, dst_base, deg_src, n, D, row_ptr, norm_d, csr_e);

    const int gemm_blocks = (n + 63) / 64;
    const int spmm_blocks = (n + 3) / 4;   // one wave per node

    // --- layer 0: x1 = relu([nd*A(ns*x) | A x] @ [W0;R0] + b0) ---
    spmm_pre<<<spmm_blocks, 256, 0, stream>>>(Xb, row_ptr, csr_e, norm_d, U, n);
    gemm_mfma<128, true, true><<<gemm_blocks, 256, 0, stream>>>(U, n, Wf0, gc_b0, X1b);

    // --- layer 1 ---
    spmm_pre<<<spmm_blocks, 256, 0, stream>>>(X1b, row_ptr, csr_e, norm_d, U, n);
    gemm_mfma<128, true, true><<<gemm_blocks, 256, 0, stream>>>(U, n, Wf1, gc_b1, X1b);

    // --- layer 2: output 64-wide fp32, no relu ---
    spmm_pre<<<spmm_blocks, 256, 0, stream>>>(X1b, row_ptr, csr_e, norm_d, U, n);
    gemm_mfma<64, false, false><<<gemm_blocks, 256, 0, stream>>>(U, n, Wf2, gc_b2, out);
}

// Round 7
// 489.126 us; speedup vs baseline: 1.0372x; 1.0372x over previous
//
#include <hip/hip_runtime.h>
#include <cstdint>
#include <cstddef>

#define NFEAT 128
#define KBUCK 1024

typedef __attribute__((ext_vector_type(8))) short bf16x8;
typedef __attribute__((ext_vector_type(4))) float f32x4;

// bf16 <-> f32 helpers (RNE, no NaN handling needed — activations are finite)
__device__ __forceinline__ unsigned short f2bf(float x) {
    union { float f; unsigned u; } v; v.f = x;
    unsigned r = v.u + 0x7fffu + ((v.u >> 16) & 1u);
    return (unsigned short)(r >> 16);
}
__device__ __forceinline__ float bf2f(unsigned short b) {
    union { unsigned u; float f; } v; v.u = ((unsigned)b) << 16;
    return v.f;
}
__device__ __forceinline__ float u2f(unsigned u) {
    union { unsigned u; float f; } v; v.u = u; return v.f;
}

// ---------------- preprocessing kernels ----------------

// one launch zeroes: dst_btot+src_btot (contiguous 2K), Xb row n, X1b row n, csr_e slack
__global__ __launch_bounds__(256) void zero_multi(
    int* __restrict__ a, int na, int* __restrict__ b, int nb,
    int* __restrict__ c, int nc, int* __restrict__ d, int nd_) {
    int i = blockIdx.x * 256 + threadIdx.x;
    int st = gridDim.x * 256;
    for (int k = i; k < na; k += st) a[k] = 0;
    if (i < nb) b[i] = 0;
    if (i < nc) c[i] = 0;
    if (i < nd_) d[i] = 0;
}

__global__ void cast_bf16_kernel(const float* __restrict__ x, unsigned short* __restrict__ y, int n4) {
    int i = blockIdx.x * blockDim.x + threadIdx.x;
    if (i < n4) {
        float4 v = ((const float4*)x)[i];
        ushort4 o;
        o.x = f2bf(v.x); o.y = f2bf(v.y); o.z = f2bf(v.z); o.w = f2bf(v.w);
        ((ushort4*)y)[i] = o;
    }
}

// Pack Wcat (256 x NCOL: rows 0..127 = gcW, 128..255 = resW; fp32) into bf16 MFMA
// B-fragment order for K=256 GEMM:
// Wf[((kb*NT + nt)*64 + lane)*8 + j] = Wcat[kb*32 + (lane>>4)*8 + j][nt*16 + (lane&15)]
template <int NCOL>
__global__ void prep_wf2(const float* __restrict__ gcW, const float* __restrict__ resW,
                         unsigned short* __restrict__ Wf) {
    constexpr int NT = NCOL / 16;
    int tid = blockIdx.x * 256 + threadIdx.x;
    if (tid >= 256 * NCOL) return;
    int k = tid / NCOL, c = tid % NCOL;
    float v = (k < 128) ? gcW[k * NCOL + c] : resW[(k - 128) * NCOL + c];
    int kb = k >> 5, koff = k & 31, quad = koff >> 3, j = koff & 7;
    int nt = c >> 4, ncol = c & 15, lane = quad * 16 + ncol;
    Wf[((kb * NT + nt) * 64 + lane) * 8 + j] = f2bf(v);
}

// ---------------- fully-bucketed graph preprocessing (round-5 structure, reverted) ----------------
// Round-6 lesson: 1.6M random device-scope atomics run at ~9/cycle chip-wide (76us)
// — atomic service-rate bound, unfixable by launch config. The bucketed LDS build
// computes degrees inside existing passes for ~25us incremental.

__global__ __launch_bounds__(256) void hist_kernel(
    const int* __restrict__ src, const int* __restrict__ dst, int ne, int D,
    int* __restrict__ dst_btot, int* __restrict__ src_btot) {
    __shared__ int hd[KBUCK], hs[KBUCK];
    const int t = threadIdx.x;
    const int tile0 = blockIdx.x * 4096;
    for (int i = t; i < KBUCK; i += 256) { hd[i] = 0; hs[i] = 0; }
    __syncthreads();
    #pragma unroll
    for (int j = 0; j < 16; j++) {
        int e = tile0 + j * 256 + t;
        if (e < ne) {
            atomicAdd(&hd[(unsigned)dst[e] / (unsigned)D], 1);
            atomicAdd(&hs[(unsigned)src[e] / (unsigned)D], 1);
        }
    }
    __syncthreads();
    for (int i = t; i < KBUCK; i += 256) {
        if (hd[i]) atomicAdd(&dst_btot[i], hd[i]);
        if (hs[i]) atomicAdd(&src_btot[i], hs[i]);
    }
}

__global__ __launch_bounds__(KBUCK) void scan_buckets(
    const int* __restrict__ dst_btot, const int* __restrict__ src_btot,
    int* __restrict__ dst_base, int* __restrict__ src_base,
    int* __restrict__ dst_cursor, int* __restrict__ src_cursor,
    int* __restrict__ row_ptr, int n, int ne) {
    __shared__ int t1[KBUCK], t2[KBUCK];
    const int t = threadIdx.x;
    int v1 = dst_btot[t], v2 = src_btot[t];
    t1[t] = v1; t2[t] = v2;
    for (int off = 1; off < KBUCK; off <<= 1) {
        __syncthreads();
        int a = (t >= off) ? t1[t - off] : 0;
        int b = (t >= off) ? t2[t - off] : 0;
        __syncthreads();
        t1[t] += a; t2[t] += b;
    }
    __syncthreads();
    int e1 = t1[t] - v1, e2 = t2[t] - v2;
    dst_base[t] = e1; src_base[t] = e2;
    dst_cursor[t] = e1; src_cursor[t] = e2;
    if (t == KBUCK - 1) {
        dst_base[KBUCK] = t1[t];
        src_base[KBUCK] = t2[t];
        row_ptr[n] = ne;
    }
}

// merged dst+src partition: one pass over (src,dst), writes both ebuf and sbuf.
__global__ __launch_bounds__(256) void partition_both(
    const int* __restrict__ src, const int* __restrict__ dst, int ne, int D,
    int* __restrict__ dst_cursor, int* __restrict__ src_cursor,
    uint2* __restrict__ ebuf, unsigned* __restrict__ sbuf) {
    __shared__ int hd[KBUCK], hs[KBUCK];
    __shared__ int gbd[KBUCK], gbs[KBUCK];
    const int t = threadIdx.x;
    const int tile0 = blockIdx.x * 4096;

    for (int i = t; i < KBUCK; i += 256) { hd[i] = 0; hs[i] = 0; }
    __syncthreads();

    int s[16], d[16], rd[16], rs[16];
    #pragma unroll
    for (int j = 0; j < 16; j++) {
        int e = tile0 + j * 256 + t;
        if (e < ne) {
            s[j] = src[e];
            d[j] = dst[e];
            rd[j] = atomicAdd(&hd[(unsigned)d[j] / (unsigned)D], 1);
            rs[j] = atomicAdd(&hs[(unsigned)s[j] / (unsigned)D], 1);
        }
    }
    __syncthreads();
    for (int i = t; i < KBUCK; i += 256) {
        int c1 = hd[i]; gbd[i] = c1 ? atomicAdd(&dst_cursor[i], c1) : 0;
        int c2 = hs[i]; gbs[i] = c2 ? atomicAdd(&src_cursor[i], c2) : 0;
    }
    __syncthreads();
    #pragma unroll
    for (int j = 0; j < 16; j++) {
        int e = tile0 + j * 256 + t;
        if (e < ne) {
            ebuf[gbd[(unsigned)d[j] / (unsigned)D] + rd[j]] = make_uint2((unsigned)s[j], (unsigned)d[j]);
            sbuf[gbs[(unsigned)s[j] / (unsigned)D] + rs[j]] = (unsigned)s[j];
        }
    }
}

// build_dst emits fused CSR entries {src, norm_s[src]} (uint2): one level of random
// indirection in spmm. norm_s built first (build_src launched before build_dst).
__global__ __launch_bounds__(256) void build_dst(
    const uint2* __restrict__ ebuf, const int* __restrict__ dst_base,
    const float* __restrict__ norm_s,
    int n, int D, int* __restrict__ row_ptr, float* __restrict__ norm_d,
    uint2* __restrict__ csr_e) {
    __shared__ int cnt[128], sc[128], rp[128], rank[128];
    const int b = blockIdx.x;
    const int d_lo = b * D;
    if (d_lo >= n) return;
    const int d_hi = (d_lo + D < n) ? d_lo + D : n;
    const int e0 = dst_base[b], e1 = dst_base[b + 1];
    const int t = threadIdx.x;

    if (t < 128) { cnt[t] = 0; rank[t] = 0; }
    __syncthreads();
    for (int i = e0 + t; i < e1; i += 256)
        atomicAdd(&cnt[(int)ebuf[i].y - d_lo], 1);
    __syncthreads();
    if (t < 128) sc[t] = cnt[t];
    __syncthreads();
    for (int off = 1; off < 128; off <<= 1) {
        int v = (t < 128 && t >= off) ? sc[t - off] : 0;
        __syncthreads();
        if (t < 128) sc[t] += v;
        __syncthreads();
    }
    if (t < 128) {
        rp[t] = e0 + sc[t] - cnt[t];   // exclusive
        int d = d_lo + t;
        if (d < d_hi) {
            row_ptr[d] = rp[t];
            norm_d[d] = rsqrtf(fmaxf((float)cnt[t], 1.0f));
        }
    }
    __syncthreads();
    for (int i = e0 + t; i < e1; i += 256) {
        uint2 ed = ebuf[i];
        int dd = (int)ed.y - d_lo;
        int r = atomicAdd(&rank[dd], 1);
        csr_e[rp[dd] + r] = make_uint2(ed.x, __float_as_uint(norm_s[(int)ed.x]));
    }
}

__global__ __launch_bounds__(256) void build_src(
    const unsigned* __restrict__ sbuf, const int* __restrict__ src_base,
    int n, int D, float* __restrict__ norm_s) {
    __shared__ int cnt[128];
    const int b = blockIdx.x;
    const int d_lo = b * D;
    if (d_lo >= n) return;
    const int d_hi = (d_lo + D < n) ? d_lo + D : n;
    const int e0 = src_base[b], e1 = src_base[b + 1];
    const int t = threadIdx.x;
    if (t < 128) cnt[t] = 0;
    __syncthreads();
    for (int i = e0 + t; i < e1; i += 256)
        atomicAdd(&cnt[(int)sbuf[i] - d_lo], 1);
    __syncthreads();
    if (t < 128 && d_lo + t < d_hi)
        norm_s[d_lo + t] = rsqrtf(fmaxf((float)cnt[t], 1.0f));
}

// ---------------- aggregate-first SpMM: U = [norm_d .* (A@(norm_s.*x)) | A@x] ----------------
// Round-15: TWO nodes per wave — paired independent gather streams. spmm is
// latency-bound (51% hbm, 37% VALU, no pipe saturated): one node exposes only 16
// outstanding gathers (4KB) then stalls. Pairing nodes 2w,2w+1 doubles in-flight
// gathers to 32 (8KB) and hides node-B's SMEM entry latency under node-A's gathers.
// Body is the round-3 loop duplicated — no state machine, no per-entry readfirstlane
// (round-2 lesson). Imbalanced pairs: the shorter node's surplus chunks redirect all
// edges to the L1-hot zero row X[n] (weight 0) via the existing val/cselect path;
// entry addresses clamp to ne (csr_e has 48 zeroed slack entries).

__global__ __launch_bounds__(256) void spmm_pre(
    const unsigned short* __restrict__ X, const int* __restrict__ row_ptr,
    const uint2* __restrict__ csr_e, const float* __restrict__ norm_d,
    unsigned short* __restrict__ U, int n, int ne) {
    const int w2 = (blockIdx.x * 256 + threadIdx.x) >> 6;
    const int lane = threadIdx.x & 63;
    const int nA = w2 * 2;
    if (nA >= n) return;
    const int nB = nA + 1;
    const bool hasB = nB < n;

    const int eA0 = __builtin_amdgcn_readfirstlane(row_ptr[nA]);
    const int eA1 = __builtin_amdgcn_readfirstlane(row_ptr[nA + 1]);
    const int eB0 = eA1;
    const int eB1 = hasB ? __builtin_amdgcn_readfirstlane(row_ptr[nB + 1]) : eA1;
    const float ndA = norm_d[nA];
    const float ndB = hasB ? norm_d[nB] : 0.f;

    const int stepsA = (eA1 - eA0 + 15) >> 4;
    const int stepsB = (eB1 - eB0 + 15) >> 4;
    const int steps = stepsA > stepsB ? stepsA : stepsB;

    float apA0 = 0.f, apA1 = 0.f, asA0 = 0.f, asA1 = 0.f;
    float apB0 = 0.f, apB1 = 0.f, asB0 = 0.f, asB1 = 0.f;
    const unsigned voff = (unsigned)(lane << 2);   // byte offset within row
    const char* Xc = (const char*)X;

#define ENTRY16(CL, E0,E1_,E2,E3,E4,E5,E6,E7,E8,E9,Ea,Eb,Ec,Ed,Ee,Ef)           \
    {                                                                            \
        uint64_t ep = (uint64_t)(const char*)(csr_e + (CL));                     \
        asm volatile(                                                            \
            "s_load_dwordx2 %[o0], %[a], 0x0\n\t"                                \
            "s_load_dwordx2 %[o1], %[a], 0x8\n\t"                                \
            "s_load_dwordx2 %[o2], %[a], 0x10\n\t"                               \
            "s_load_dwordx2 %[o3], %[a], 0x18\n\t"                               \
            "s_load_dwordx2 %[o4], %[a], 0x20\n\t"                               \
            "s_load_dwordx2 %[o5], %[a], 0x28\n\t"                               \
            "s_load_dwordx2 %[o6], %[a], 0x30\n\t"                               \
            "s_load_dwordx2 %[o7], %[a], 0x38\n\t"                               \
            "s_load_dwordx2 %[o8], %[a], 0x40\n\t"                               \
            "s_load_dwordx2 %[o9], %[a], 0x48\n\t"                               \
            "s_load_dwordx2 %[oa], %[a], 0x50\n\t"                               \
            "s_load_dwordx2 %[ob], %[a], 0x58\n\t"                               \
            "s_load_dwordx2 %[oc], %[a], 0x60\n\t"                               \
            "s_load_dwordx2 %[od], %[a], 0x68\n\t"                               \
            "s_load_dwordx2 %[oe], %[a], 0x70\n\t"                               \
            "s_load_dwordx2 %[of], %[a], 0x78\n\t"                               \
            "s_waitcnt lgkmcnt(0)"                                               \
            : [o0] "=&s"(E0), [o1] "=&s"(E1_), [o2] "=&s"(E2), [o3] "=&s"(E3),   \
              [o4] "=&s"(E4), [o5] "=&s"(E5), [o6] "=&s"(E6), [o7] "=&s"(E7),    \
              [o8] "=&s"(E8), [o9] "=&s"(E9), [oa] "=&s"(Ea), [ob] "=&s"(Eb),    \
              [oc] "=&s"(Ec), [od] "=&s"(Ed), [oe] "=&s"(Ee), [of] "=&s"(Ef)     \
            : [a] "s"(ep)                                                        \
            : "memory");                                                         \
    }

#define PREP1(i, Ei, C, E1V, Q, W)                                               \
    {                                                                            \
        int sv = (int)(unsigned)(Ei);                                            \
        unsigned wu = (unsigned)((Ei) >> 32);                                    \
        const bool val = ((C) + i) < (E1V);   /* wave-uniform scalar */          \
        sv = val ? sv : n;                    /* s_cselect */                    \
        wu = val ? wu : 0u;                   /* s_cselect */                    \
        W[i] = u2f(wu);                                                          \
        unsigned off = (((unsigned)sv) << 8) + voff;                             \
        Q[i] = *(const unsigned*)(Xc + off);  /* saddr-form load */              \
    }

    for (int s = 0; s < steps; s++) {
        const int cA = eA0 + (s << 4);
        const int cB = eB0 + (s << 4);
        const int cAL = cA < ne ? cA : ne;    // clamp into csr_e+slack
        const int cBL = cB < ne ? cB : ne;

        unsigned qA[16], qB[16];
        float wvA[16], wvB[16];

        {   // ---- node A: entries + gathers ----
            uint64_t E0, E1, E2, E3, E4, E5, E6, E7, E8, E9, Ea, Eb, Ec, Ed, Ee, Ef;
            ENTRY16(cAL, E0,E1,E2,E3,E4,E5,E6,E7,E8,E9,Ea,Eb,Ec,Ed,Ee,Ef)
            PREP1(0, E0, cA, eA1, qA, wvA)  PREP1(1, E1, cA, eA1, qA, wvA)
            PREP1(2, E2, cA, eA1, qA, wvA)  PREP1(3, E3, cA, eA1, qA, wvA)
            PREP1(4, E4, cA, eA1, qA, wvA)  PREP1(5, E5, cA, eA1, qA, wvA)
            PREP1(6, E6, cA, eA1, qA, wvA)  PREP1(7, E7, cA, eA1, qA, wvA)
            PREP1(8, E8, cA, eA1, qA, wvA)  PREP1(9, E9, cA, eA1, qA, wvA)
            PREP1(10, Ea, cA, eA1, qA, wvA) PREP1(11, Eb, cA, eA1, qA, wvA)
            PREP1(12, Ec, cA, eA1, qA, wvA) PREP1(13, Ed, cA, eA1, qA, wvA)
            PREP1(14, Ee, cA, eA1, qA, wvA) PREP1(15, Ef, cA, eA1, qA, wvA)
        }
        {   // ---- node B: entries (SMEM latency hides under A's gathers) + gathers ----
            uint64_t E0, E1, E2, E3, E4, E5, E6, E7, E8, E9, Ea, Eb, Ec, Ed, Ee, Ef;
            ENTRY16(cBL, E0,E1,E2,E3,E4,E5,E6,E7,E8,E9,Ea,Eb,Ec,Ed,Ee,Ef)
            PREP1(0, E0, cB, eB1, qB, wvB)  PREP1(1, E1, cB, eB1, qB, wvB)
            PREP1(2, E2, cB, eB1, qB, wvB)  PREP1(3, E3, cB, eB1, qB, wvB)
            PREP1(4, E4, cB, eB1, qB, wvB)  PREP1(5, E5, cB, eB1, qB, wvB)
            PREP1(6, E6, cB, eB1, qB, wvB)  PREP1(7, E7, cB, eB1, qB, wvB)
            PREP1(8, E8, cB, eB1, qB, wvB)  PREP1(9, E9, cB, eB1, qB, wvB)
            PREP1(10, Ea, cB, eB1, qB, wvB) PREP1(11, Eb, cB, eB1, qB, wvB)
            PREP1(12, Ec, cB, eB1, qB, wvB) PREP1(13, Ed, cB, eB1, qB, wvB)
            PREP1(14, Ee, cB, eB1, qB, wvB) PREP1(15, Ef, cB, eB1, qB, wvB)
        }

        #pragma unroll
        for (int i = 0; i < 16; i++) {
            unsigned qq = qA[i];
            float x0 = u2f(qq << 16);
            float x1 = u2f(qq & 0xffff0000u);
            apA0 += x0; apA1 += x1;
            asA0 = fmaf(wvA[i], x0, asA0);
            asA1 = fmaf(wvA[i], x1, asA1);
        }
        #pragma unroll
        for (int i = 0; i < 16; i++) {
            unsigned qq = qB[i];
            float x0 = u2f(qq << 16);
            float x1 = u2f(qq & 0xffff0000u);
            apB0 += x0; apB1 += x1;
            asB0 = fmaf(wvB[i], x0, asB0);
            asB1 = fmaf(wvB[i], x1, asB1);
        }
    }
#undef ENTRY16
#undef PREP1

    {
        ushort2 gc, rs;
        gc.x = f2bf(ndA * asA0); gc.y = f2bf(ndA * asA1);
        rs.x = f2bf(apA0);       rs.y = f2bf(apA1);
        unsigned short* Ur = U + (size_t)nA * 256;
        *(ushort2*)(Ur + lane * 2) = gc;
        *(ushort2*)(Ur + 128 + lane * 2) = rs;
    }
    if (hasB) {
        ushort2 gc, rs;
        gc.x = f2bf(ndB * asB0); gc.y = f2bf(ndB * asB1);
        rs.x = f2bf(apB0);       rs.y = f2bf(apB1);
        unsigned short* Ur = U + (size_t)nB * 256;
        *(ushort2*)(Ur + lane * 2) = gc;
        *(ushort2*)(Ur + 128 + lane * 2) = rs;
    }
}

// ---------------- MFMA GEMM: y = U @ [W;R] + b (+relu), K=256 ----------------
// Round-4 structure verbatim: NO LDS staging — Wf is 64KB and L2-resident;
// B-fragments load straight from global per MFMA. U: [M,256] bf16; Wf
// fragment-major (prep_wf2). mfma_f32_16x16x32_bf16 layouts (HW-verified m89/m91):
// A[m=lane&15][k=(lane>>4)*8+j], C/D col=lane&15, row=(lane>>4)*4+reg.

template <int NCOL, bool RELU, bool OUT_BF16>
__global__ __launch_bounds__(256) void gemm_mfma(
    const unsigned short* __restrict__ U, int M,
    const unsigned short* __restrict__ Wf,
    const float* __restrict__ bias, void* __restrict__ outv) {
    constexpr int NT = NCOL / 16;

    const int t = threadIdx.x;
    const int wave = t >> 6, lane = t & 63;
    const int r0 = blockIdx.x * 64 + wave * 16;

    // A fragments (rows am = r0 + (lane&15), k = kb*32 + (lane>>4)*8 + j)
    const int am = r0 + (lane & 15);
    const int kq = (lane >> 4) * 8;
    bf16x8 afrag[8];
    if (am < M) {
        const unsigned short* ap = U + (size_t)am * 256 + kq;
        #pragma unroll
        for (int kb = 0; kb < 8; kb++)
            afrag[kb] = *(const bf16x8*)(ap + kb * 32);
    } else {
        #pragma unroll
        for (int kb = 0; kb < 8; kb++) afrag[kb] = bf16x8{};
    }

    const int orow = r0 + (lane >> 4) * 4;
    const bf16x8* Wv = (const bf16x8*)Wf;

    #pragma unroll 1
    for (int nt = 0; nt < NT; nt++) {
        f32x4 acc = {0.f, 0.f, 0.f, 0.f};
        #pragma unroll
        for (int kb = 0; kb < 8; kb++) {
            bf16x8 b = Wv[(kb * NT + nt) * 64 + lane];
            acc = __builtin_amdgcn_mfma_f32_16x16x32_bf16(afrag[kb], b, acc, 0, 0, 0);
        }
        const int gcol = nt * 16 + (lane & 15);
        const float bv = bias[gcol];
        #pragma unroll
        for (int r = 0; r < 4; r++) {
            int gm = orow + r;
            if (gm < M) {
                float v = acc[r] + bv;
                if (RELU) v = fmaxf(v, 0.f);
                if constexpr (OUT_BF16)
                    ((unsigned short*)outv)[(size_t)gm * NCOL + gcol] = f2bf(v);
                else
                    ((float*)outv)[(size_t)gm * NCOL + gcol] = v;
            }
        }
    }
}

// ---------------- launch ----------------

extern "C" void kernel_launch(void* const* d_in, const int* in_sizes, int n_in,
                              void* d_out, int out_size, void* d_ws, size_t ws_size,
                              hipStream_t stream) {
    const float* raw_x  = (const float*)d_in[0];
    const int*   src    = (const int*)d_in[1];
    const int*   dst    = (const int*)d_in[2];
    const float* gc_w0  = (const float*)d_in[3];
    const float* gc_b0  = (const float*)d_in[4];
    const float* gc_w1  = (const float*)d_in[5];
    const float* gc_b1  = (const float*)d_in[6];
    const float* gc_w2  = (const float*)d_in[7];
    const float* gc_b2  = (const float*)d_in[8];
    const float* res_w0 = (const float*)d_in[9];
    const float* res_w1 = (const float*)d_in[10];
    const float* res_w2 = (const float*)d_in[11];

    const int n  = in_sizes[0] / NFEAT;   // 100000
    const int ne = in_sizes[1];           // 1600000
    float* out = (float*)d_out;
    const int D = (n + KBUCK - 1) / KBUCK;   // nodes per bucket (98, <=128)

    // workspace layout (Xb/X1b have an extra zeroed row n; csr_e has 48 slack entries)
    char* w = (char*)d_ws;
    unsigned short* U   = (unsigned short*)w; w += (size_t)n * 256 * sizeof(unsigned short);       // 51.2 MB
    unsigned short* Xb  = (unsigned short*)w; w += (size_t)(n + 1) * 128 * sizeof(unsigned short); // 25.6 MB
    unsigned short* X1b = (unsigned short*)w; w += (size_t)(n + 1) * 128 * sizeof(unsigned short); // 25.6 MB
    float* norm_s = (float*)w;   w += (size_t)n * sizeof(float);
    float* norm_d = (float*)w;   w += (size_t)n * sizeof(float);
    int* row_ptr = (int*)w;      w += (size_t)(n + 1) * sizeof(int);
    uint2* csr_e = (uint2*)w;    w += (size_t)(ne + 48) * sizeof(uint2);   // 12.8 MB {src, ns}
    uint2* ebuf = (uint2*)w;     w += (size_t)ne * sizeof(uint2);          // 12.8 MB
    unsigned* sbuf = (unsigned*)w; w += (size_t)ne * sizeof(unsigned);     // 6.4 MB
    int* dst_btot = (int*)w;     w += KBUCK * sizeof(int);
    int* src_btot = (int*)w;     w += KBUCK * sizeof(int);   // contiguous with dst_btot
    int* dst_base = (int*)w;     w += (KBUCK + 1) * sizeof(int);
    int* src_base = (int*)w;     w += (KBUCK + 1) * sizeof(int);
    int* dst_cursor = (int*)w;   w += KBUCK * sizeof(int);
    int* src_cursor = (int*)w;   w += KBUCK * sizeof(int);
    unsigned short* Wf0 = (unsigned short*)w; w += 256 * 128 * sizeof(unsigned short);
    unsigned short* Wf1 = (unsigned short*)w; w += 256 * 128 * sizeof(unsigned short);
    unsigned short* Wf2 = (unsigned short*)w; w += 256 * 64 * sizeof(unsigned short);

    const int tiles = (ne + 4095) / 4096;

    // --- preprocessing: bf16 cast, weight fragments, bucketed CSR + degrees ---
    cast_bf16_kernel<<<(n * (NFEAT / 4) + 255) / 256, 256, 0, stream>>>(raw_x, Xb, n * (NFEAT / 4));
    zero_multi<<<8, 256, 0, stream>>>(
        dst_btot, 2 * KBUCK,                       // dst_btot + src_btot contiguous
        (int*)(Xb + (size_t)n * 128), 64,
        (int*)(X1b + (size_t)n * 128), 64,
        (int*)(csr_e + ne), 96);
    prep_wf2<128><<<128, 256, 0, stream>>>(gc_w0, res_w0, Wf0);
    prep_wf2<128><<<128, 256, 0, stream>>>(gc_w1, res_w1, Wf1);
    prep_wf2<64><<<64, 256, 0, stream>>>(gc_w2, res_w2, Wf2);
    hist_kernel<<<tiles, 256, 0, stream>>>(src, dst, ne, D, dst_btot, src_btot);
    scan_buckets<<<1, KBUCK, 0, stream>>>(dst_btot, src_btot, dst_base, src_base,
                                          dst_cursor, src_cursor, row_ptr, n, ne);
    partition_both<<<tiles, 256, 0, stream>>>(src, dst, ne, D, dst_cursor, src_cursor, ebuf, sbuf);
    build_src<<<KBUCK, 256, 0, stream>>>(sbuf, src_base, n, D, norm_s);
    build_dst<<<KBUCK, 256, 0, stream>>>(ebuf, dst_base, norm_s, n, D, row_ptr, norm_d, csr_e);

    const int gemm_blocks = (n + 63) / 64;
    const int nwaves = (n + 1) / 2;                    // two nodes per wave
    const int spmm_blocks = (nwaves + 3) / 4;

    // --- layer 0: x1 = relu([nd*A(ns*x) | A x] @ [W0;R0] + b0) ---
    spmm_pre<<<spmm_blocks, 256, 0, stream>>>(Xb, row_ptr, csr_e, norm_d, U, n, ne);
    gemm_mfma<128, true, true><<<gemm_blocks, 256, 0, stream>>>(U, n, Wf0, gc_b0, X1b);

    // --- layer 1 ---
    spmm_pre<<<spmm_blocks, 256, 0, stream>>>(X1b, row_ptr, csr_e, norm_d, U, n, ne);
    gemm_mfma<128, true, true><<<gemm_blocks, 256, 0, stream>>>(U, n, Wf1, gc_b1, X1b);

    // --- layer 2: output 64-wide fp32, no relu ---
    spmm_pre<<<spmm_blocks, 256, 0, stream>>>(X1b, row_ptr, csr_e, norm_d, U, n, ne);
    gemm_mfma<64, false, false><<<gemm_blocks, 256, 0, stream>>>(U, n, Wf2, gc_b2, out);
}

// Round 8
// 416.361 us; speedup vs baseline: 1.2185x; 1.1748x over previous
//
#include <hip/hip_runtime.h>
#include <cstdint>
#include <cstddef>

#define NFEAT 128
#define KBUCK 1024

typedef __attribute__((ext_vector_type(8))) short bf16x8;
typedef __attribute__((ext_vector_type(4))) float f32x4;

// bf16 <-> f32 helpers (RNE)
__device__ __forceinline__ unsigned short f2bf(float x) {
    union { float f; unsigned u; } v; v.f = x;
    unsigned r = v.u + 0x7fffu + ((v.u >> 16) & 1u);
    return (unsigned short)(r >> 16);
}
__device__ __forceinline__ float u2f(unsigned u) {
    union { unsigned u; float f; } v; v.u = u; return v.f;
}

// ---------------- preprocessing kernels ----------------

// one launch zeroes: dst_btot+src_btot (contiguous 2K), X0q row n, X1q row n, csr_e slack
__global__ __launch_bounds__(256) void zero_multi(
    int* __restrict__ a, int na, int* __restrict__ b, int nb,
    int* __restrict__ c, int nc, int* __restrict__ d, int nd_) {
    int i = blockIdx.x * 256 + threadIdx.x;
    int st = gridDim.x * 256;
    for (int k = i; k < na; k += st) a[k] = 0;
    if (i < nb) b[i] = 0;
    if (i < nc) c[i] = 0;
    if (i < nd_) d[i] = 0;
}

// f32 -> fp8 e4m3 (HW cvt, RNE): 4 floats -> 4 bytes per thread
__global__ void cast_fp8_kernel(const float* __restrict__ x, unsigned* __restrict__ y, int n4) {
    int i = blockIdx.x * blockDim.x + threadIdx.x;
    if (i < n4) {
        float4 v = ((const float4*)x)[i];
        int p = 0;
        p = __builtin_amdgcn_cvt_pk_fp8_f32(v.x, v.y, p, false);
        p = __builtin_amdgcn_cvt_pk_fp8_f32(v.z, v.w, p, true);
        y[i] = (unsigned)p;
    }
}

// Pack Wcat (256 x NCOL: rows 0..127 = gcW, 128..255 = resW; fp32) into bf16 MFMA
// B-fragment order for K=256 GEMM:
// Wf[((kb*NT + nt)*64 + lane)*8 + j] = Wcat[kb*32 + (lane>>4)*8 + j][nt*16 + (lane&15)]
template <int NCOL>
__global__ void prep_wf2(const float* __restrict__ gcW, const float* __restrict__ resW,
                         unsigned short* __restrict__ Wf) {
    constexpr int NT = NCOL / 16;
    int tid = blockIdx.x * 256 + threadIdx.x;
    if (tid >= 256 * NCOL) return;
    int k = tid / NCOL, c = tid % NCOL;
    float v = (k < 128) ? gcW[k * NCOL + c] : resW[(k - 128) * NCOL + c];
    int kb = k >> 5, koff = k & 31, quad = koff >> 3, j = koff & 7;
    int nt = c >> 4, ncol = c & 15, lane = quad * 16 + ncol;
    Wf[((kb * NT + nt) * 64 + lane) * 8 + j] = f2bf(v);
}

// ---------------- fully-bucketed graph preprocessing (round-5 structure) ----------------
// Round-6 lesson: 1.6M random device-scope atomics run at ~9/cycle chip-wide (76us)
// — atomic service-rate bound. The bucketed LDS build computes degrees inside
// existing passes for ~25us incremental.

__global__ __launch_bounds__(256) void hist_kernel(
    const int* __restrict__ src, const int* __restrict__ dst, int ne, int D,
    int* __restrict__ dst_btot, int* __restrict__ src_btot) {
    __shared__ int hd[KBUCK], hs[KBUCK];
    const int t = threadIdx.x;
    const int tile0 = blockIdx.x * 4096;
    for (int i = t; i < KBUCK; i += 256) { hd[i] = 0; hs[i] = 0; }
    __syncthreads();
    #pragma unroll
    for (int j = 0; j < 16; j++) {
        int e = tile0 + j * 256 + t;
        if (e < ne) {
            atomicAdd(&hd[(unsigned)dst[e] / (unsigned)D], 1);
            atomicAdd(&hs[(unsigned)src[e] / (unsigned)D], 1);
        }
    }
    __syncthreads();
    for (int i = t; i < KBUCK; i += 256) {
        if (hd[i]) atomicAdd(&dst_btot[i], hd[i]);
        if (hs[i]) atomicAdd(&src_btot[i], hs[i]);
    }
}

__global__ __launch_bounds__(KBUCK) void scan_buckets(
    const int* __restrict__ dst_btot, const int* __restrict__ src_btot,
    int* __restrict__ dst_base, int* __restrict__ src_base,
    int* __restrict__ dst_cursor, int* __restrict__ src_cursor,
    int* __restrict__ row_ptr, int n, int ne) {
    __shared__ int t1[KBUCK], t2[KBUCK];
    const int t = threadIdx.x;
    int v1 = dst_btot[t], v2 = src_btot[t];
    t1[t] = v1; t2[t] = v2;
    for (int off = 1; off < KBUCK; off <<= 1) {
        __syncthreads();
        int a = (t >= off) ? t1[t - off] : 0;
        int b = (t >= off) ? t2[t - off] : 0;
        __syncthreads();
        t1[t] += a; t2[t] += b;
    }
    __syncthreads();
    int e1 = t1[t] - v1, e2 = t2[t] - v2;
    dst_base[t] = e1; src_base[t] = e2;
    dst_cursor[t] = e1; src_cursor[t] = e2;
    if (t == KBUCK - 1) {
        dst_base[KBUCK] = t1[t];
        src_base[KBUCK] = t2[t];
        row_ptr[n] = ne;
    }
}

// merged dst+src partition: one pass over (src,dst), writes both ebuf and sbuf.
__global__ __launch_bounds__(256) void partition_both(
    const int* __restrict__ src, const int* __restrict__ dst, int ne, int D,
    int* __restrict__ dst_cursor, int* __restrict__ src_cursor,
    uint2* __restrict__ ebuf, unsigned* __restrict__ sbuf) {
    __shared__ int hd[KBUCK], hs[KBUCK];
    __shared__ int gbd[KBUCK], gbs[KBUCK];
    const int t = threadIdx.x;
    const int tile0 = blockIdx.x * 4096;

    for (int i = t; i < KBUCK; i += 256) { hd[i] = 0; hs[i] = 0; }
    __syncthreads();

    int s[16], d[16], rd[16], rs[16];
    #pragma unroll
    for (int j = 0; j < 16; j++) {
        int e = tile0 + j * 256 + t;
        if (e < ne) {
            s[j] = src[e];
            d[j] = dst[e];
            rd[j] = atomicAdd(&hd[(unsigned)d[j] / (unsigned)D], 1);
            rs[j] = atomicAdd(&hs[(unsigned)s[j] / (unsigned)D], 1);
        }
    }
    __syncthreads();
    for (int i = t; i < KBUCK; i += 256) {
        int c1 = hd[i]; gbd[i] = c1 ? atomicAdd(&dst_cursor[i], c1) : 0;
        int c2 = hs[i]; gbs[i] = c2 ? atomicAdd(&src_cursor[i], c2) : 0;
    }
    __syncthreads();
    #pragma unroll
    for (int j = 0; j < 16; j++) {
        int e = tile0 + j * 256 + t;
        if (e < ne) {
            ebuf[gbd[(unsigned)d[j] / (unsigned)D] + rd[j]] = make_uint2((unsigned)s[j], (unsigned)d[j]);
            sbuf[gbs[(unsigned)s[j] / (unsigned)D] + rs[j]] = (unsigned)s[j];
        }
    }
}

// build_dst emits fused CSR entries {src, norm_s[src]} (uint2). norm_s built first.
__global__ __launch_bounds__(256) void build_dst(
    const uint2* __restrict__ ebuf, const int* __restrict__ dst_base,
    const float* __restrict__ norm_s,
    int n, int D, int* __restrict__ row_ptr, float* __restrict__ norm_d,
    uint2* __restrict__ csr_e) {
    __shared__ int cnt[128], sc[128], rp[128], rank[128];
    const int b = blockIdx.x;
    const int d_lo = b * D;
    if (d_lo >= n) return;
    const int d_hi = (d_lo + D < n) ? d_lo + D : n;
    const int e0 = dst_base[b], e1 = dst_base[b + 1];
    const int t = threadIdx.x;

    if (t < 128) { cnt[t] = 0; rank[t] = 0; }
    __syncthreads();
    for (int i = e0 + t; i < e1; i += 256)
        atomicAdd(&cnt[(int)ebuf[i].y - d_lo], 1);
    __syncthreads();
    if (t < 128) sc[t] = cnt[t];
    __syncthreads();
    for (int off = 1; off < 128; off <<= 1) {
        int v = (t < 128 && t >= off) ? sc[t - off] : 0;
        __syncthreads();
        if (t < 128) sc[t] += v;
        __syncthreads();
    }
    if (t < 128) {
        rp[t] = e0 + sc[t] - cnt[t];   // exclusive
        int d = d_lo + t;
        if (d < d_hi) {
            row_ptr[d] = rp[t];
            norm_d[d] = rsqrtf(fmaxf((float)cnt[t], 1.0f));
        }
    }
    __syncthreads();
    for (int i = e0 + t; i < e1; i += 256) {
        uint2 ed = ebuf[i];
        int dd = (int)ed.y - d_lo;
        int r = atomicAdd(&rank[dd], 1);
        csr_e[rp[dd] + r] = make_uint2(ed.x, __float_as_uint(norm_s[(int)ed.x]));
    }
}

__global__ __launch_bounds__(256) void build_src(
    const unsigned* __restrict__ sbuf, const int* __restrict__ src_base,
    int n, int D, float* __restrict__ norm_s) {
    __shared__ int cnt[128];
    const int b = blockIdx.x;
    const int d_lo = b * D;
    if (d_lo >= n) return;
    const int d_hi = (d_lo + D < n) ? d_lo + D : n;
    const int e0 = src_base[b], e1 = src_base[b + 1];
    const int t = threadIdx.x;
    if (t < 128) cnt[t] = 0;
    __syncthreads();
    for (int i = e0 + t; i < e1; i += 256)
        atomicAdd(&cnt[(int)sbuf[i] - d_lo], 1);
    __syncthreads();
    if (t < 128 && d_lo + t < d_hi)
        norm_s[d_lo + t] = rsqrtf(fmaxf((float)cnt[t], 1.0f));
}

// ---------------- aggregate-first SpMM (fp8 gather): U = [nd.*(A@(ns.*x)) | A@x] ----------------
// Round-16: spmm is BYTE-SERVICE bound (~4 TB/s TCC plateau across 5 structures;
// round-7's doubled in-flight requests were null). Lever: halve the bytes. X is fp8
// e4m3 (rows 128B, not 256B). Round-3 single-node structure verbatim otherwise (best
// measured): SMEM entry loads, zero-row redirect, saddr 2B gathers, f32 accumulate,
// bf16 U output (MFMA input precision unchanged). Decode = 1 v_cvt_pk_f32_fp8 per
// edge (cheaper than the 2 bf16 shifts it replaces).

__global__ __launch_bounds__(256) void spmm_pre(
    const unsigned char* __restrict__ X, const int* __restrict__ row_ptr,
    const uint2* __restrict__ csr_e, const float* __restrict__ norm_d,
    unsigned short* __restrict__ U, int n) {
    const int wid = (blockIdx.x * 256 + threadIdx.x) >> 6;
    const int lane = threadIdx.x & 63;
    if (wid >= n) return;

    const int e0 = __builtin_amdgcn_readfirstlane(row_ptr[wid]);
    const int e1 = __builtin_amdgcn_readfirstlane(row_ptr[wid + 1]);
    const float nd = norm_d[wid];

    float ap0 = 0.f, ap1 = 0.f, as0 = 0.f, as1 = 0.f;
    const unsigned voff = (unsigned)(lane << 1);   // byte offset within 128B fp8 row
    const char* Xc = (const char*)X;

    for (int c = e0; c < e1; c += 16) {
        uint64_t E0, E1, E2, E3, E4, E5, E6, E7, E8, E9, Ea, Eb, Ec, Ed, Ee, Ef;
        {
            uint64_t ep = (uint64_t)(const char*)(csr_e + c);
            asm volatile(
                "s_load_dwordx2 %[o0], %[a], 0x0\n\t"
                "s_load_dwordx2 %[o1], %[a], 0x8\n\t"
                "s_load_dwordx2 %[o2], %[a], 0x10\n\t"
                "s_load_dwordx2 %[o3], %[a], 0x18\n\t"
                "s_load_dwordx2 %[o4], %[a], 0x20\n\t"
                "s_load_dwordx2 %[o5], %[a], 0x28\n\t"
                "s_load_dwordx2 %[o6], %[a], 0x30\n\t"
                "s_load_dwordx2 %[o7], %[a], 0x38\n\t"
                "s_load_dwordx2 %[o8], %[a], 0x40\n\t"
                "s_load_dwordx2 %[o9], %[a], 0x48\n\t"
                "s_load_dwordx2 %[oa], %[a], 0x50\n\t"
                "s_load_dwordx2 %[ob], %[a], 0x58\n\t"
                "s_load_dwordx2 %[oc], %[a], 0x60\n\t"
                "s_load_dwordx2 %[od], %[a], 0x68\n\t"
                "s_load_dwordx2 %[oe], %[a], 0x70\n\t"
                "s_load_dwordx2 %[of], %[a], 0x78\n\t"
                "s_waitcnt lgkmcnt(0)"
                : [o0] "=&s"(E0), [o1] "=&s"(E1), [o2] "=&s"(E2), [o3] "=&s"(E3),
                  [o4] "=&s"(E4), [o5] "=&s"(E5), [o6] "=&s"(E6), [o7] "=&s"(E7),
                  [o8] "=&s"(E8), [o9] "=&s"(E9), [oa] "=&s"(Ea), [ob] "=&s"(Eb),
                  [oc] "=&s"(Ec), [od] "=&s"(Ed), [oe] "=&s"(Ee), [of] "=&s"(Ef)
                : [a] "s"(ep)
                : "memory");
        }

        unsigned q[16];
        float wv[16];

#define PREP(i, Ei)                                                             \
        {                                                                       \
            int sv = (int)(unsigned)(Ei);                                       \
            unsigned wu = (unsigned)((Ei) >> 32);                               \
            const bool val = (c + i) < e1;      /* wave-uniform scalar */       \
            sv = val ? sv : n;                  /* s_cselect */                 \
            wu = val ? wu : 0u;                 /* s_cselect */                 \
            wv[i] = u2f(wu);                                                    \
            unsigned off = (((unsigned)sv) << 7) + voff;                        \
            q[i] = *(const unsigned short*)(Xc + off);   /* 2 fp8 = 2 cols */   \
        }
        PREP(0, E0)  PREP(1, E1)  PREP(2, E2)  PREP(3, E3)
        PREP(4, E4)  PREP(5, E5)  PREP(6, E6)  PREP(7, E7)
        PREP(8, E8)  PREP(9, E9)  PREP(10, Ea) PREP(11, Eb)
        PREP(12, Ec) PREP(13, Ed) PREP(14, Ee) PREP(15, Ef)
#undef PREP

        #pragma unroll
        for (int i = 0; i < 16; i++) {
            auto xy = __builtin_amdgcn_cvt_pk_f32_fp8((int)q[i], false);
            float x0 = xy[0], x1 = xy[1];
            ap0 += x0; ap1 += x1;
            as0 = fmaf(wv[i], x0, as0);
            as1 = fmaf(wv[i], x1, as1);
        }
    }

    ushort2 gc, rs;
    gc.x = f2bf(nd * as0); gc.y = f2bf(nd * as1);
    rs.x = f2bf(ap0);      rs.y = f2bf(ap1);
    unsigned short* Ur = U + (size_t)wid * 256;
    *(ushort2*)(Ur + lane * 2) = gc;
    *(ushort2*)(Ur + 128 + lane * 2) = rs;
}

// ---------------- MFMA GEMM: y = U @ [W;R] + b (+relu), K=256 ----------------
// Round-4 structure: NO LDS staging — Wf is 64KB and L2-resident; B-fragments load
// straight from global per MFMA. U: [M,256] bf16; Wf fragment-major (prep_wf2).
// OUTMODE: 0 = f32 (final layer), 1 = fp8 bytes (next layer's gather source).
// mfma_f32_16x16x32_bf16 layouts (HW-verified m89/m91): A[m=lane&15][k=(lane>>4)*8+j],
// C/D col=lane&15, row=(lane>>4)*4+reg.

template <int NCOL, bool RELU, int OUTMODE>
__global__ __launch_bounds__(256) void gemm_mfma(
    const unsigned short* __restrict__ U, int M,
    const unsigned short* __restrict__ Wf,
    const float* __restrict__ bias, void* __restrict__ outv) {
    constexpr int NT = NCOL / 16;

    const int t = threadIdx.x;
    const int wave = t >> 6, lane = t & 63;
    const int r0 = blockIdx.x * 64 + wave * 16;

    // A fragments (rows am = r0 + (lane&15), k = kb*32 + (lane>>4)*8 + j)
    const int am = r0 + (lane & 15);
    const int kq = (lane >> 4) * 8;
    bf16x8 afrag[8];
    if (am < M) {
        const unsigned short* ap = U + (size_t)am * 256 + kq;
        #pragma unroll
        for (int kb = 0; kb < 8; kb++)
            afrag[kb] = *(const bf16x8*)(ap + kb * 32);
    } else {
        #pragma unroll
        for (int kb = 0; kb < 8; kb++) afrag[kb] = bf16x8{};
    }

    const int orow = r0 + (lane >> 4) * 4;
    const bf16x8* Wv = (const bf16x8*)Wf;

    #pragma unroll 1
    for (int nt = 0; nt < NT; nt++) {
        f32x4 acc = {0.f, 0.f, 0.f, 0.f};
        #pragma unroll
        for (int kb = 0; kb < 8; kb++) {
            bf16x8 b = Wv[(kb * NT + nt) * 64 + lane];
            acc = __builtin_amdgcn_mfma_f32_16x16x32_bf16(afrag[kb], b, acc, 0, 0, 0);
        }
        const int gcol = nt * 16 + (lane & 15);
        const float bv = bias[gcol];
        #pragma unroll
        for (int r = 0; r < 4; r++) {
            int gm = orow + r;
            if (gm < M) {
                float v = acc[r] + bv;
                if (RELU) v = fmaxf(v, 0.f);
                if constexpr (OUTMODE == 0) {
                    ((float*)outv)[(size_t)gm * NCOL + gcol] = v;
                } else {
                    int p = __builtin_amdgcn_cvt_pk_fp8_f32(v, v, 0, false);
                    ((unsigned char*)outv)[(size_t)gm * NCOL + gcol] = (unsigned char)(p & 0xff);
                }
            }
        }
    }
}

// ---------------- launch ----------------

extern "C" void kernel_launch(void* const* d_in, const int* in_sizes, int n_in,
                              void* d_out, int out_size, void* d_ws, size_t ws_size,
                              hipStream_t stream) {
    const float* raw_x  = (const float*)d_in[0];
    const int*   src    = (const int*)d_in[1];
    const int*   dst    = (const int*)d_in[2];
    const float* gc_w0  = (const float*)d_in[3];
    const float* gc_b0  = (const float*)d_in[4];
    const float* gc_w1  = (const float*)d_in[5];
    const float* gc_b1  = (const float*)d_in[6];
    const float* gc_w2  = (const float*)d_in[7];
    const float* gc_b2  = (const float*)d_in[8];
    const float* res_w0 = (const float*)d_in[9];
    const float* res_w1 = (const float*)d_in[10];
    const float* res_w2 = (const float*)d_in[11];

    const int n  = in_sizes[0] / NFEAT;   // 100000
    const int ne = in_sizes[1];           // 1600000
    float* out = (float*)d_out;
    const int D = (n + KBUCK - 1) / KBUCK;   // nodes per bucket (98, <=128)

    // workspace layout. X0q/X1q are fp8 activation buffers (128B rows, +1 zeroed
    // row n = spmm pad-redirect target); they ping-pong L0:X0->X1, L1:X1->X0,
    // L2:X0->out. csr_e has 48 zeroed slack entries.
    char* w = (char*)d_ws;
    unsigned short* U  = (unsigned short*)w; w += (size_t)n * 256 * sizeof(unsigned short); // 51.2 MB
    unsigned char* X0q = (unsigned char*)w;  w += (size_t)(n + 1) * 128;                    // 12.8 MB
    unsigned char* X1q = (unsigned char*)w;  w += (size_t)(n + 1) * 128;                    // 12.8 MB
    float* norm_s = (float*)w;   w += (size_t)n * sizeof(float);
    float* norm_d = (float*)w;   w += (size_t)n * sizeof(float);
    int* row_ptr = (int*)w;      w += (size_t)(n + 1) * sizeof(int);
    uint2* csr_e = (uint2*)w;    w += (size_t)(ne + 48) * sizeof(uint2);   // 12.8 MB {src, ns}
    uint2* ebuf = (uint2*)w;     w += (size_t)ne * sizeof(uint2);          // 12.8 MB
    unsigned* sbuf = (unsigned*)w; w += (size_t)ne * sizeof(unsigned);     // 6.4 MB
    int* dst_btot = (int*)w;     w += KBUCK * sizeof(int);
    int* src_btot = (int*)w;     w += KBUCK * sizeof(int);   // contiguous with dst_btot
    int* dst_base = (int*)w;     w += (KBUCK + 1) * sizeof(int);
    int* src_base = (int*)w;     w += (KBUCK + 1) * sizeof(int);
    int* dst_cursor = (int*)w;   w += KBUCK * sizeof(int);
    int* src_cursor = (int*)w;   w += KBUCK * sizeof(int);
    unsigned short* Wf0 = (unsigned short*)w; w += 256 * 128 * sizeof(unsigned short);
    unsigned short* Wf1 = (unsigned short*)w; w += 256 * 128 * sizeof(unsigned short);
    unsigned short* Wf2 = (unsigned short*)w; w += 256 * 64 * sizeof(unsigned short);

    const int tiles = (ne + 4095) / 4096;

    // --- preprocessing: fp8 cast, weight fragments, bucketed CSR + degrees ---
    cast_fp8_kernel<<<(n * 32 + 255) / 256, 256, 0, stream>>>(raw_x, (unsigned*)X0q, n * 32);
    zero_multi<<<8, 256, 0, stream>>>(
        dst_btot, 2 * KBUCK,                       // dst_btot + src_btot contiguous
        (int*)(X0q + (size_t)n * 128), 32,
        (int*)(X1q + (size_t)n * 128), 32,
        (int*)(csr_e + ne), 96);
    prep_wf2<128><<<128, 256, 0, stream>>>(gc_w0, res_w0, Wf0);
    prep_wf2<128><<<128, 256, 0, stream>>>(gc_w1, res_w1, Wf1);
    prep_wf2<64><<<64, 256, 0, stream>>>(gc_w2, res_w2, Wf2);
    hist_kernel<<<tiles, 256, 0, stream>>>(src, dst, ne, D, dst_btot, src_btot);
    scan_buckets<<<1, KBUCK, 0, stream>>>(dst_btot, src_btot, dst_base, src_base,
                                          dst_cursor, src_cursor, row_ptr, n, ne);
    partition_both<<<tiles, 256, 0, stream>>>(src, dst, ne, D, dst_cursor, src_cursor, ebuf, sbuf);
    build_src<<<KBUCK, 256, 0, stream>>>(sbuf, src_base, n, D, norm_s);
    build_dst<<<KBUCK, 256, 0, stream>>>(ebuf, dst_base, norm_s, n, D, row_ptr, norm_d, csr_e);

    const int gemm_blocks = (n + 63) / 64;
    const int spmm_blocks = (n + 3) / 4;   // one wave per node

    // --- layer 0: x1 = relu([nd*A(ns*x) | A x] @ [W0;R0] + b0) -> fp8 X1q ---
    spmm_pre<<<spmm_blocks, 256, 0, stream>>>(X0q, row_ptr, csr_e, norm_d, U, n);
    gemm_mfma<128, true, 1><<<gemm_blocks, 256, 0, stream>>>(U, n, Wf0, gc_b0, X1q);

    // --- layer 1 -> fp8 X0q (row n untouched: still zero) ---
    spmm_pre<<<spmm_blocks, 256, 0, stream>>>(X1q, row_ptr, csr_e, norm_d, U, n);
    gemm_mfma<128, true, 1><<<gemm_blocks, 256, 0, stream>>>(U, n, Wf1, gc_b1, X0q);

    // --- layer 2: output 64-wide fp32, no relu ---
    spmm_pre<<<spmm_blocks, 256, 0, stream>>>(X0q, row_ptr, csr_e, norm_d, U, n);
    gemm_mfma<64, false, 0><<<gemm_blocks, 256, 0, stream>>>(U, n, Wf2, gc_b2, out);
}

// Round 9
// 392.091 us; speedup vs baseline: 1.2939x; 1.0619x over previous
//
#include <hip/hip_runtime.h>
#include <cstdint>
#include <cstddef>

#define NFEAT 128
#define KBUCK 1024

typedef __attribute__((ext_vector_type(8))) short bf16x8;
typedef __attribute__((ext_vector_type(4))) float f32x4;

// bf16 <-> f32 helpers (RNE)
__device__ __forceinline__ unsigned short f2bf(float x) {
    union { float f; unsigned u; } v; v.f = x;
    unsigned r = v.u + 0x7fffu + ((v.u >> 16) & 1u);
    return (unsigned short)(r >> 16);
}
__device__ __forceinline__ float u2f(unsigned u) {
    union { unsigned u; float f; } v; v.u = u; return v.f;
}

// ---------------- preprocessing kernels ----------------

// one launch zeroes: dst_btot+src_btot (contiguous 2K), X0q row n, X1q row n, csr_e slack
__global__ __launch_bounds__(256) void zero_multi(
    int* __restrict__ a, int na, int* __restrict__ b, int nb,
    int* __restrict__ c, int nc, int* __restrict__ d, int nd_) {
    int i = blockIdx.x * 256 + threadIdx.x;
    int st = gridDim.x * 256;
    for (int k = i; k < na; k += st) a[k] = 0;
    if (i < nb) b[i] = 0;
    if (i < nc) c[i] = 0;
    if (i < nd_) d[i] = 0;
}

// f32 -> fp8 e4m3 (HW cvt, RNE): 4 floats -> 4 bytes per thread
__global__ void cast_fp8_kernel(const float* __restrict__ x, unsigned* __restrict__ y, int n4) {
    int i = blockIdx.x * blockDim.x + threadIdx.x;
    if (i < n4) {
        float4 v = ((const float4*)x)[i];
        int p = 0;
        p = __builtin_amdgcn_cvt_pk_fp8_f32(v.x, v.y, p, false);
        p = __builtin_amdgcn_cvt_pk_fp8_f32(v.z, v.w, p, true);
        y[i] = (unsigned)p;
    }
}

// Pack Wcat (256 x NCOL: rows 0..127 = gcW, 128..255 = resW; fp32) into bf16 MFMA
// B-fragment order for K=256 GEMM:
// Wf[((kb*NT + nt)*64 + lane)*8 + j] = Wcat[kb*32 + (lane>>4)*8 + j][nt*16 + (lane&15)]
template <int NCOL>
__global__ void prep_wf2(const float* __restrict__ gcW, const float* __restrict__ resW,
                         unsigned short* __restrict__ Wf) {
    constexpr int NT = NCOL / 16;
    int tid = blockIdx.x * 256 + threadIdx.x;
    if (tid >= 256 * NCOL) return;
    int k = tid / NCOL, c = tid % NCOL;
    float v = (k < 128) ? gcW[k * NCOL + c] : resW[(k - 128) * NCOL + c];
    int kb = k >> 5, koff = k & 31, quad = koff >> 3, j = koff & 7;
    int nt = c >> 4, ncol = c & 15, lane = quad * 16 + ncol;
    Wf[((kb * NT + nt) * 64 + lane) * 8 + j] = f2bf(v);
}

// ---------------- fully-bucketed graph preprocessing ----------------
// Round-6 lesson: random device-scope atomics are service-rate bound (~9/cyc chip).
// Round-8 lesson: scattered 8B record writes are sector-amplified 5x (94MB for
// 19MB payload). Round-9: stage records in LDS in bucket order, write coalesced runs.

__global__ __launch_bounds__(256) void hist_kernel(
    const int* __restrict__ src, const int* __restrict__ dst, int ne, int D,
    int* __restrict__ dst_btot, int* __restrict__ src_btot) {
    __shared__ int hd[KBUCK], hs[KBUCK];
    const int t = threadIdx.x;
    const int tile0 = blockIdx.x * 4096;
    for (int i = t; i < KBUCK; i += 256) { hd[i] = 0; hs[i] = 0; }
    __syncthreads();
    #pragma unroll
    for (int j = 0; j < 16; j++) {
        int e = tile0 + j * 256 + t;
        if (e < ne) {
            atomicAdd(&hd[(unsigned)dst[e] / (unsigned)D], 1);
            atomicAdd(&hs[(unsigned)src[e] / (unsigned)D], 1);
        }
    }
    __syncthreads();
    for (int i = t; i < KBUCK; i += 256) {
        if (hd[i]) atomicAdd(&dst_btot[i], hd[i]);
        if (hs[i]) atomicAdd(&src_btot[i], hs[i]);
    }
}

__global__ __launch_bounds__(KBUCK) void scan_buckets(
    const int* __restrict__ dst_btot, const int* __restrict__ src_btot,
    int* __restrict__ dst_base, int* __restrict__ src_base,
    int* __restrict__ dst_cursor, int* __restrict__ src_cursor,
    int* __restrict__ row_ptr, int n, int ne) {
    __shared__ int t1[KBUCK], t2[KBUCK];
    const int t = threadIdx.x;
    int v1 = dst_btot[t], v2 = src_btot[t];
    t1[t] = v1; t2[t] = v2;
    for (int off = 1; off < KBUCK; off <<= 1) {
        __syncthreads();
        int a = (t >= off) ? t1[t - off] : 0;
        int b = (t >= off) ? t2[t - off] : 0;
        __syncthreads();
        t1[t] += a; t2[t] += b;
    }
    __syncthreads();
    int e1 = t1[t] - v1, e2 = t2[t] - v2;
    dst_base[t] = e1; src_base[t] = e2;
    dst_cursor[t] = e1; src_cursor[t] = e2;
    if (t == KBUCK - 1) {
        dst_base[KBUCK] = t1[t];
        src_base[KBUCK] = t2[t];
        row_ptr[n] = ne;
    }
}

// merged dst+src partition with LDS bucket-order staging and coalesced run writes.
// 1024 threads, 4 edges each (4096-edge tile). LDS 72KB -> 2 blocks/CU cap.
__global__ __launch_bounds__(KBUCK) void partition_both(
    const int* __restrict__ src, const int* __restrict__ dst, int ne, int D,
    int* __restrict__ dst_cursor, int* __restrict__ src_cursor,
    uint2* __restrict__ ebuf, unsigned* __restrict__ sbuf) {
    __shared__ int hd[KBUCK], hs[KBUCK];     // per-bucket tile counts
    __shared__ int sd[KBUCK], ss[KBUCK];     // inclusive scans
    __shared__ int gbd[KBUCK], gbs[KBUCK];   // global bases
    __shared__ uint2 estage[4096];           // 32 KB
    __shared__ unsigned sstage[4096];        // 16 KB
    const int t = threadIdx.x;
    const int tile0 = blockIdx.x * 4096;

    hd[t] = 0; hs[t] = 0;
    __syncthreads();

    int s[4], d[4], rd[4], rs[4];
    #pragma unroll
    for (int j = 0; j < 4; j++) {
        int e = tile0 + j * KBUCK + t;
        if (e < ne) {
            s[j] = src[e];
            d[j] = dst[e];
            rd[j] = atomicAdd(&hd[(unsigned)d[j] / (unsigned)D], 1);
            rs[j] = atomicAdd(&hs[(unsigned)s[j] / (unsigned)D], 1);
        }
    }
    __syncthreads();

    // inclusive scans of hd, hs
    sd[t] = hd[t]; ss[t] = hs[t];
    for (int off = 1; off < KBUCK; off <<= 1) {
        __syncthreads();
        int a = (t >= off) ? sd[t - off] : 0;
        int b = (t >= off) ? ss[t - off] : 0;
        __syncthreads();
        sd[t] += a; ss[t] += b;
    }
    __syncthreads();

    // reserve global space per bucket
    gbd[t] = hd[t] ? atomicAdd(&dst_cursor[t], hd[t]) : 0;
    gbs[t] = hs[t] ? atomicAdd(&src_cursor[t], hs[t]) : 0;
    __syncthreads();

    // stage records in bucket order (exclusive start = sd[b]-hd[b])
    #pragma unroll
    for (int j = 0; j < 4; j++) {
        int e = tile0 + j * KBUCK + t;
        if (e < ne) {
            int bd = (int)((unsigned)d[j] / (unsigned)D);
            estage[(sd[bd] - hd[bd]) + rd[j]] = make_uint2((unsigned)s[j], (unsigned)d[j]);
            int bs = (int)((unsigned)s[j] / (unsigned)D);
            sstage[(ss[bs] - hs[bs]) + rs[j]] = (unsigned)s[j];
        }
    }
    __syncthreads();

    // coalesced run writes: consecutive k -> consecutive addresses within a run
    const int total = sd[KBUCK - 1];
    for (int k = t; k < total; k += KBUCK) {
        uint2 ed = estage[k];
        int b = (int)(ed.y / (unsigned)D);
        ebuf[gbd[b] + (k - (sd[b] - hd[b]))] = ed;
        unsigned sv = sstage[k];
        int b2 = (int)(sv / (unsigned)D);
        sbuf[gbs[b2] + (k - (ss[b2] - hs[b2]))] = sv;
    }
}

// build_dst: counting-sort the bucket into LDS staging, then stream the contiguous
// [e0,e1) csr_e range linearly (coalesced). Emits {src, norm_s[src]} entries.
__global__ __launch_bounds__(256) void build_dst(
    const uint2* __restrict__ ebuf, const int* __restrict__ dst_base,
    const float* __restrict__ norm_s,
    int n, int D, int* __restrict__ row_ptr, float* __restrict__ norm_d,
    uint2* __restrict__ csr_e) {
    __shared__ int cnt[128], sc[128], rp[128], rank[128];
    __shared__ uint2 stage[4608];   // 36 KB; bucket avg ~1562, cap generous
    const int b = blockIdx.x;
    const int d_lo = b * D;
    if (d_lo >= n) return;
    const int d_hi = (d_lo + D < n) ? d_lo + D : n;
    const int e0 = dst_base[b], e1 = dst_base[b + 1];
    const int m = e1 - e0;
    const int t = threadIdx.x;

    if (t < 128) { cnt[t] = 0; rank[t] = 0; }
    __syncthreads();
    for (int i = e0 + t; i < e1; i += 256)
        atomicAdd(&cnt[(int)ebuf[i].y - d_lo], 1);
    __syncthreads();
    if (t < 128) sc[t] = cnt[t];
    __syncthreads();
    for (int off = 1; off < 128; off <<= 1) {
        int v = (t < 128 && t >= off) ? sc[t - off] : 0;
        __syncthreads();
        if (t < 128) sc[t] += v;
        __syncthreads();
    }
    if (t < 128) {
        rp[t] = e0 + sc[t] - cnt[t];   // exclusive global row start
        int d = d_lo + t;
        if (d < d_hi) {
            row_ptr[d] = rp[t];
            norm_d[d] = rsqrtf(fmaxf((float)cnt[t], 1.0f));
        }
    }
    __syncthreads();

    if (m <= 4608) {
        for (int i = e0 + t; i < e1; i += 256) {
            uint2 ed = ebuf[i];
            int dd = (int)ed.y - d_lo;
            int r = atomicAdd(&rank[dd], 1);
            stage[(sc[dd] - cnt[dd]) + r] = make_uint2(ed.x, __float_as_uint(norm_s[(int)ed.x]));
        }
        __syncthreads();
        for (int k = t; k < m; k += 256)
            csr_e[e0 + k] = stage[k];          // streaming, coalesced
    } else {
        for (int i = e0 + t; i < e1; i += 256) {
            uint2 ed = ebuf[i];
            int dd = (int)ed.y - d_lo;
            int r = atomicAdd(&rank[dd], 1);
            csr_e[rp[dd] + r] = make_uint2(ed.x, __float_as_uint(norm_s[(int)ed.x]));
        }
    }
}

__global__ __launch_bounds__(256) void build_src(
    const unsigned* __restrict__ sbuf, const int* __restrict__ src_base,
    int n, int D, float* __restrict__ norm_s) {
    __shared__ int cnt[128];
    const int b = blockIdx.x;
    const int d_lo = b * D;
    if (d_lo >= n) return;
    const int d_hi = (d_lo + D < n) ? d_lo + D : n;
    const int e0 = src_base[b], e1 = src_base[b + 1];
    const int t = threadIdx.x;
    if (t < 128) cnt[t] = 0;
    __syncthreads();
    for (int i = e0 + t; i < e1; i += 256)
        atomicAdd(&cnt[(int)sbuf[i] - d_lo], 1);
    __syncthreads();
    if (t < 128 && d_lo + t < d_hi)
        norm_s[d_lo + t] = rsqrtf(fmaxf((float)cnt[t], 1.0f));
}

// ---------------- aggregate-first SpMM (fp8 gather): U = [nd.*(A@(ns.*x)) | A@x] ----------------
// Round-8: spmm is BYTE-SERVICE bound; fp8 e4m3 rows (128B) halved gather bytes.
// Round-3 single-node structure otherwise: SMEM entry loads, zero-row redirect,
// saddr 2B gathers, f32 accumulate, bf16 U output.

__global__ __launch_bounds__(256) void spmm_pre(
    const unsigned char* __restrict__ X, const int* __restrict__ row_ptr,
    const uint2* __restrict__ csr_e, const float* __restrict__ norm_d,
    unsigned short* __restrict__ U, int n) {
    const int wid = (blockIdx.x * 256 + threadIdx.x) >> 6;
    const int lane = threadIdx.x & 63;
    if (wid >= n) return;

    const int e0 = __builtin_amdgcn_readfirstlane(row_ptr[wid]);
    const int e1 = __builtin_amdgcn_readfirstlane(row_ptr[wid + 1]);
    const float nd = norm_d[wid];

    float ap0 = 0.f, ap1 = 0.f, as0 = 0.f, as1 = 0.f;
    const unsigned voff = (unsigned)(lane << 1);   // byte offset within 128B fp8 row
    const char* Xc = (const char*)X;

    for (int c = e0; c < e1; c += 16) {
        uint64_t E0, E1, E2, E3, E4, E5, E6, E7, E8, E9, Ea, Eb, Ec, Ed, Ee, Ef;
        {
            uint64_t ep = (uint64_t)(const char*)(csr_e + c);
            asm volatile(
                "s_load_dwordx2 %[o0], %[a], 0x0\n\t"
                "s_load_dwordx2 %[o1], %[a], 0x8\n\t"
                "s_load_dwordx2 %[o2], %[a], 0x10\n\t"
                "s_load_dwordx2 %[o3], %[a], 0x18\n\t"
                "s_load_dwordx2 %[o4], %[a], 0x20\n\t"
                "s_load_dwordx2 %[o5], %[a], 0x28\n\t"
                "s_load_dwordx2 %[o6], %[a], 0x30\n\t"
                "s_load_dwordx2 %[o7], %[a], 0x38\n\t"
                "s_load_dwordx2 %[o8], %[a], 0x40\n\t"
                "s_load_dwordx2 %[o9], %[a], 0x48\n\t"
                "s_load_dwordx2 %[oa], %[a], 0x50\n\t"
                "s_load_dwordx2 %[ob], %[a], 0x58\n\t"
                "s_load_dwordx2 %[oc], %[a], 0x60\n\t"
                "s_load_dwordx2 %[od], %[a], 0x68\n\t"
                "s_load_dwordx2 %[oe], %[a], 0x70\n\t"
                "s_load_dwordx2 %[of], %[a], 0x78\n\t"
                "s_waitcnt lgkmcnt(0)"
                : [o0] "=&s"(E0), [o1] "=&s"(E1), [o2] "=&s"(E2), [o3] "=&s"(E3),
                  [o4] "=&s"(E4), [o5] "=&s"(E5), [o6] "=&s"(E6), [o7] "=&s"(E7),
                  [o8] "=&s"(E8), [o9] "=&s"(E9), [oa] "=&s"(Ea), [ob] "=&s"(Eb),
                  [oc] "=&s"(Ec), [od] "=&s"(Ed), [oe] "=&s"(Ee), [of] "=&s"(Ef)
                : [a] "s"(ep)
                : "memory");
        }

        unsigned q[16];
        float wv[16];

#define PREP(i, Ei)                                                             \
        {                                                                       \
            int sv = (int)(unsigned)(Ei);                                       \
            unsigned wu = (unsigned)((Ei) >> 32);                               \
            const bool val = (c + i) < e1;      /* wave-uniform scalar */       \
            sv = val ? sv : n;                  /* s_cselect */                 \
            wu = val ? wu : 0u;                 /* s_cselect */                 \
            wv[i] = u2f(wu);                                                    \
            unsigned off = (((unsigned)sv) << 7) + voff;                        \
            q[i] = *(const unsigned short*)(Xc + off);   /* 2 fp8 = 2 cols */   \
        }
        PREP(0, E0)  PREP(1, E1)  PREP(2, E2)  PREP(3, E3)
        PREP(4, E4)  PREP(5, E5)  PREP(6, E6)  PREP(7, E7)
        PREP(8, E8)  PREP(9, E9)  PREP(10, Ea) PREP(11, Eb)
        PREP(12, Ec) PREP(13, Ed) PREP(14, Ee) PREP(15, Ef)
#undef PREP

        #pragma unroll
        for (int i = 0; i < 16; i++) {
            auto xy = __builtin_amdgcn_cvt_pk_f32_fp8((int)q[i], false);
            float x0 = xy[0], x1 = xy[1];
            ap0 += x0; ap1 += x1;
            as0 = fmaf(wv[i], x0, as0);
            as1 = fmaf(wv[i], x1, as1);
        }
    }

    ushort2 gc, rs;
    gc.x = f2bf(nd * as0); gc.y = f2bf(nd * as1);
    rs.x = f2bf(ap0);      rs.y = f2bf(ap1);
    unsigned short* Ur = U + (size_t)wid * 256;
    *(ushort2*)(Ur + lane * 2) = gc;
    *(ushort2*)(Ur + 128 + lane * 2) = rs;
}

// ---------------- MFMA GEMM: y = U @ [W;R] + b (+relu), K=256 ----------------
// Round-4 structure: NO LDS staging — Wf is 64KB and L2-resident; B-fragments load
// straight from global per MFMA. OUTMODE: 0 = f32 (final), 1 = fp8 bytes.
// mfma_f32_16x16x32_bf16 layouts (HW-verified m89/m91): A[m=lane&15][k=(lane>>4)*8+j],
// C/D col=lane&15, row=(lane>>4)*4+reg.

template <int NCOL, bool RELU, int OUTMODE>
__global__ __launch_bounds__(256) void gemm_mfma(
    const unsigned short* __restrict__ U, int M,
    const unsigned short* __restrict__ Wf,
    const float* __restrict__ bias, void* __restrict__ outv) {
    constexpr int NT = NCOL / 16;

    const int t = threadIdx.x;
    const int wave = t >> 6, lane = t & 63;
    const int r0 = blockIdx.x * 64 + wave * 16;

    // A fragments (rows am = r0 + (lane&15), k = kb*32 + (lane>>4)*8 + j)
    const int am = r0 + (lane & 15);
    const int kq = (lane >> 4) * 8;
    bf16x8 afrag[8];
    if (am < M) {
        const unsigned short* ap = U + (size_t)am * 256 + kq;
        #pragma unroll
        for (int kb = 0; kb < 8; kb++)
            afrag[kb] = *(const bf16x8*)(ap + kb * 32);
    } else {
        #pragma unroll
        for (int kb = 0; kb < 8; kb++) afrag[kb] = bf16x8{};
    }

    const int orow = r0 + (lane >> 4) * 4;
    const bf16x8* Wv = (const bf16x8*)Wf;

    #pragma unroll 1
    for (int nt = 0; nt < NT; nt++) {
        f32x4 acc = {0.f, 0.f, 0.f, 0.f};
        #pragma unroll
        for (int kb = 0; kb < 8; kb++) {
            bf16x8 b = Wv[(kb * NT + nt) * 64 + lane];
            acc = __builtin_amdgcn_mfma_f32_16x16x32_bf16(afrag[kb], b, acc, 0, 0, 0);
        }
        const int gcol = nt * 16 + (lane & 15);
        const float bv = bias[gcol];
        #pragma unroll
        for (int r = 0; r < 4; r++) {
            int gm = orow + r;
            if (gm < M) {
                float v = acc[r] + bv;
                if (RELU) v = fmaxf(v, 0.f);
                if constexpr (OUTMODE == 0) {
                    ((float*)outv)[(size_t)gm * NCOL + gcol] = v;
                } else {
                    int p = __builtin_amdgcn_cvt_pk_fp8_f32(v, v, 0, false);
                    ((unsigned char*)outv)[(size_t)gm * NCOL + gcol] = (unsigned char)(p & 0xff);
                }
            }
        }
    }
}

// ---------------- launch ----------------

extern "C" void kernel_launch(void* const* d_in, const int* in_sizes, int n_in,
                              void* d_out, int out_size, void* d_ws, size_t ws_size,
                              hipStream_t stream) {
    const float* raw_x  = (const float*)d_in[0];
    const int*   src    = (const int*)d_in[1];
    const int*   dst    = (const int*)d_in[2];
    const float* gc_w0  = (const float*)d_in[3];
    const float* gc_b0  = (const float*)d_in[4];
    const float* gc_w1  = (const float*)d_in[5];
    const float* gc_b1  = (const float*)d_in[6];
    const float* gc_w2  = (const float*)d_in[7];
    const float* gc_b2  = (const float*)d_in[8];
    const float* res_w0 = (const float*)d_in[9];
    const float* res_w1 = (const float*)d_in[10];
    const float* res_w2 = (const float*)d_in[11];

    const int n  = in_sizes[0] / NFEAT;   // 100000
    const int ne = in_sizes[1];           // 1600000
    float* out = (float*)d_out;
    const int D = (n + KBUCK - 1) / KBUCK;   // nodes per bucket (98, <=128)

    // workspace layout. X0q/X1q are fp8 activation buffers (128B rows, +1 zeroed
    // row n = spmm pad-redirect target); ping-pong L0:X0->X1, L1:X1->X0, L2:X0->out.
    char* w = (char*)d_ws;
    unsigned short* U  = (unsigned short*)w; w += (size_t)n * 256 * sizeof(unsigned short); // 51.2 MB
    unsigned char* X0q = (unsigned char*)w;  w += (size_t)(n + 1) * 128;                    // 12.8 MB
    unsigned char* X1q = (unsigned char*)w;  w += (size_t)(n + 1) * 128;                    // 12.8 MB
    float* norm_s = (float*)w;   w += (size_t)n * sizeof(float);
    float* norm_d = (float*)w;   w += (size_t)n * sizeof(float);
    int* row_ptr = (int*)w;      w += (size_t)(n + 1) * sizeof(int);
    uint2* csr_e = (uint2*)w;    w += (size_t)(ne + 48) * sizeof(uint2);   // 12.8 MB {src, ns}
    uint2* ebuf = (uint2*)w;     w += (size_t)ne * sizeof(uint2);          // 12.8 MB
    unsigned* sbuf = (unsigned*)w; w += (size_t)ne * sizeof(unsigned);     // 6.4 MB
    int* dst_btot = (int*)w;     w += KBUCK * sizeof(int);
    int* src_btot = (int*)w;     w += KBUCK * sizeof(int);   // contiguous with dst_btot
    int* dst_base = (int*)w;     w += (KBUCK + 1) * sizeof(int);
    int* src_base = (int*)w;     w += (KBUCK + 1) * sizeof(int);
    int* dst_cursor = (int*)w;   w += KBUCK * sizeof(int);
    int* src_cursor = (int*)w;   w += KBUCK * sizeof(int);
    unsigned short* Wf0 = (unsigned short*)w; w += 256 * 128 * sizeof(unsigned short);
    unsigned short* Wf1 = (unsigned short*)w; w += 256 * 128 * sizeof(unsigned short);
    unsigned short* Wf2 = (unsigned short*)w; w += 256 * 64 * sizeof(unsigned short);

    const int tiles = (ne + 4095) / 4096;

    // --- preprocessing: fp8 cast, weight fragments, bucketed CSR + degrees ---
    cast_fp8_kernel<<<(n * 32 + 255) / 256, 256, 0, stream>>>(raw_x, (unsigned*)X0q, n * 32);
    zero_multi<<<8, 256, 0, stream>>>(
        dst_btot, 2 * KBUCK,                       // dst_btot + src_btot contiguous
        (int*)(X0q + (size_t)n * 128), 32,
        (int*)(X1q + (size_t)n * 128), 32,
        (int*)(csr_e + ne), 96);
    prep_wf2<128><<<128, 256, 0, stream>>>(gc_w0, res_w0, Wf0);
    prep_wf2<128><<<128, 256, 0, stream>>>(gc_w1, res_w1, Wf1);
    prep_wf2<64><<<64, 256, 0, stream>>>(gc_w2, res_w2, Wf2);
    hist_kernel<<<tiles, 256, 0, stream>>>(src, dst, ne, D, dst_btot, src_btot);
    scan_buckets<<<1, KBUCK, 0, stream>>>(dst_btot, src_btot, dst_base, src_base,
                                          dst_cursor, src_cursor, row_ptr, n, ne);
    partition_both<<<tiles, KBUCK, 0, stream>>>(src, dst, ne, D, dst_cursor, src_cursor, ebuf, sbuf);
    build_src<<<KBUCK, 256, 0, stream>>>(sbuf, src_base, n, D, norm_s);
    build_dst<<<KBUCK, 256, 0, stream>>>(ebuf, dst_base, norm_s, n, D, row_ptr, norm_d, csr_e);

    const int gemm_blocks = (n + 63) / 64;
    const int spmm_blocks = (n + 3) / 4;   // one wave per node

    // --- layer 0: x1 = relu([nd*A(ns*x) | A x] @ [W0;R0] + b0) -> fp8 X1q ---
    spmm_pre<<<spmm_blocks, 256, 0, stream>>>(X0q, row_ptr, csr_e, norm_d, U, n);
    gemm_mfma<128, true, 1><<<gemm_blocks, 256, 0, stream>>>(U, n, Wf0, gc_b0, X1q);

    // --- layer 1 -> fp8 X0q (row n untouched: still zero) ---
    spmm_pre<<<spmm_blocks, 256, 0, stream>>>(X1q, row_ptr, csr_e, norm_d, U, n);
    gemm_mfma<128, true, 1><<<gemm_blocks, 256, 0, stream>>>(U, n, Wf1, gc_b1, X0q);

    // --- layer 2: output 64-wide fp32, no relu ---
    spmm_pre<<<spmm_blocks, 256, 0, stream>>>(X0q, row_ptr, csr_e, norm_d, U, n);
    gemm_mfma<64, false, 0><<<gemm_blocks, 256, 0, stream>>>(U, n, Wf2, gc_b2, out);
}